// Round 4
// baseline (349.749 us; speedup 1.0000x reference)
//
#include <hip/hip_runtime.h>
#include <math.h>
#include <float.h>

#define BATCH 16
#define SEQ 96
#define NNODE 256
#define CFREQ 9
#define MNODE (NNODE * CFREQ)      // 2304
#define BM (BATCH * MNODE)         // 36864
#define KNN 8
#define EMBED 128
#define HIDDEN 64
#define TN (SEQ * NNODE)           // 24576
#define KCAP 64

__constant__ float COS16[16] = {
    1.0f, 0.9238795325112867f, 0.7071067811865476f, 0.3826834323650898f,
    0.0f, -0.3826834323650898f, -0.7071067811865476f, -0.9238795325112867f,
    -1.0f, -0.9238795325112867f, -0.7071067811865476f, -0.3826834323650898f,
    0.0f, 0.3826834323650898f, 0.7071067811865476f, 0.9238795325112867f};
__constant__ float SIN16[16] = {
    0.0f, 0.3826834323650898f, 0.7071067811865476f, 0.9238795325112867f,
    1.0f, 0.9238795325112867f, 0.7071067811865476f, 0.3826834323650898f,
    0.0f, -0.3826834323650898f, -0.7071067811865476f, -0.9238795325112867f,
    -1.0f, -0.9238795325112867f, -0.7071067811865476f, -0.3826834323650898f};

static __device__ __forceinline__ float silu_f(float x) {
    return x / (1.0f + expf(-x));
}

// trend[b,t,n] = (x[t-1]+x[t]+x[t+1])/3 with edge clamp; layout (B,T,N)
__global__ void trend_kernel(const float* __restrict__ x, float* __restrict__ trend) {
    int gid = blockIdx.x * blockDim.x + threadIdx.x;
    if (gid >= BATCH * TN) return;
    int b = gid / TN;
    int rem = gid - b * TN;
    int t = rem / NNODE;
    int n = rem - t * NNODE;
    int tm = t > 0 ? t - 1 : 0;
    int tp = t < SEQ - 1 ? t + 1 : SEQ - 1;
    const float* xb = x + b * TN;
    float v = (xb[tm * NNODE + n] + xb[t * NNODE + n] + xb[tp * NNODE + n]) * (1.0f / 3.0f);
    trend[gid] = v;
}

// S[b, m] = ortho-rfft16 of (x - trend) over first 16 t; m = n*9 + c
__global__ void fft_kernel(const float* __restrict__ x, const float* __restrict__ trend,
                           float* __restrict__ S) {
    int gid = blockIdx.x * blockDim.x + threadIdx.x;
    if (gid >= BM) return;
    int b = gid / MNODE;
    int m = gid - b * MNODE;
    int n = m / CFREQ;
    int c = m - n * CFREQ;
    const float* xb = x + b * TN + n;
    const float* tb = trend + b * TN + n;
    float re = 0.0f, im = 0.0f;
    #pragma unroll
    for (int t = 0; t < 16; ++t) {
        float s = xb[t * NNODE] - tb[t * NNODE];
        int k = (c * t) & 15;
        re += s * COS16[k];
        im -= s * SIN16[k];
    }
    S[gid * 2 + 0] = re * 0.25f;
    S[gid * 2 + 1] = im * 0.25f;
}

// One WAVE per row, 4 rows per 256-block. Exact top-8, VALU-minimized:
//  Ranking value h_j = sq[j] - 2*(fi . fj)  (monotone with d = sqi + h:
//  f32 add with wave-constant sqi is monotone non-decreasing, so ordering
//  and tie structure used for selection are preserved; keys remain unique
//  via the index low-bits). sq[] precomputed once in LDS at staging.
//  P1: streaming per-lane min of h over 36 candidates. Self-exclusion is
//      scalarized: i is wave-uniform -> (k_i, lane_i) via readfirstlane;
//      only iteration k==k_i (scalar branch) does the lane test.
//  T : max over 8 disjoint 8-lane groups of group-min of lane minima
//      (6 shuffles). >=8 candidates have h <= T => T >= true h8.
//  P2: recompute h (bit-identical expression), survivors append their u64
//      key (sortable_h | j) via wave-private LDS atomicAdd counter
//      (round-0-proven; pays VALU only on survivor iterations; same-wave
//      LDS ops are in-order so no barrier is needed).
//  P3 (guarded: KNN <= total <= KCAP): rank selection over the tiny
//      survivor list via broadcast ds_reads; unique keys -> unique ranks
//      0..7 written from initialized slots only.
//  Any other total -> exact full-scan fallback (insert network + 8-round
//      extract-min merge), also on h for consistency.
__global__ void __launch_bounds__(256, 5) knn_kernel(const float* __restrict__ S,
                                                     int* __restrict__ idx, int* __restrict__ cnt) {
    __shared__ float2 f[MNODE];                        // 18432 B
    __shared__ float  sq[MNODE];                       // 9216 B
    __shared__ unsigned long long kbuf[4][KCAP];       // 2048 B
    __shared__ int bcnt[4];
    int b = blockIdx.y;
    int tid = threadIdx.x;
    int wave = tid >> 6, lane = tid & 63;
    if (lane == 0) bcnt[wave] = 0;
    for (int t = tid; t < MNODE; t += 256) {
        float xx = S[(b * MNODE + t) * 2 + 0];
        float yy = S[(b * MNODE + t) * 2 + 1];
        f[t] = make_float2(xx, yy);
        sq[t] = __fadd_rn(__fmul_rn(xx, xx), __fmul_rn(yy, yy));
    }
    __syncthreads();
    int i = blockIdx.x * 4 + wave;
    float2 fi = f[i];
    float xi2 = -2.0f * fi.x, yi2 = -2.0f * fi.y;
    int lane_i = __builtin_amdgcn_readfirstlane(i & 63);
    int k_i    = __builtin_amdgcn_readfirstlane(i >> 6);

    // Phase 1: per-lane min of h over 36 candidates (streaming)
    float mymin = FLT_MAX;
    #pragma unroll 12
    for (int k = 0; k < 36; ++k) {
        int j = lane + (k << 6);
        float2 fj = f[j];
        float h = __fmaf_rn(xi2, fj.x, __fmaf_rn(yi2, fj.y, sq[j]));
        if (k == k_i) h = (lane == lane_i) ? FLT_MAX : h;
        mymin = fminf(mymin, h);
    }
    // Threshold: 6 dependent shuffles. Group-min (lanes differing in bits 0-2),
    // then max across the 8 groups (bits 3-5).
    float g = mymin;
    g = fminf(g, __shfl_xor(g, 1, 64));
    g = fminf(g, __shfl_xor(g, 2, 64));
    g = fminf(g, __shfl_xor(g, 4, 64));
    float T = g;
    T = fmaxf(T, __shfl_xor(T, 8, 64));
    T = fmaxf(T, __shfl_xor(T, 16, 64));
    T = fmaxf(T, __shfl_xor(T, 32, 64));
    // Phase 2: recompute h, atomic-append survivors' exact keys (wave-private)
    unsigned long long* mybuf = kbuf[wave];
    #pragma unroll 12
    for (int k = 0; k < 36; ++k) {
        int j = lane + (k << 6);
        float2 fj = f[j];
        float h = __fmaf_rn(xi2, fj.x, __fmaf_rn(yi2, fj.y, sq[j]));
        if (k == k_i) h = (lane == lane_i) ? FLT_MAX : h;
        if (h <= T) {
            unsigned int bits = __float_as_uint(h);
            if (bits == 0x80000000u) bits = 0u;
            unsigned int s = bits ^ (unsigned int)(((int)bits >> 31) | 0x80000000);
            int pos = atomicAdd(&bcnt[wave], 1);
            if (pos < KCAP) mybuf[pos] = ((unsigned long long)s << 32) | (unsigned int)j;
        }
    }
    int total = bcnt[wave];   // same-wave LDS ops are in-order; no barrier

    if (total >= KNN && total <= KCAP) {
        // Phase 3: rank selection over the survivor list (broadcast reads)
        for (int p = lane; p < total; p += 64) {
            unsigned long long mykey = mybuf[p];
            int rank = 0;
            for (int q = 0; q < total; ++q) {
                rank += (mybuf[q] < mykey) ? 1 : 0;
            }
            if (rank < KNN) {
                int j = (int)(unsigned int)(mykey & 0xFFFFFFFFull);
                idx[(b * MNODE + i) * KNN + rank] = j;
                atomicAdd(&cnt[b * MNODE + j], 1);
            }
        }
    } else {
        // exact fallback: full recompute scan, per-lane insert network +
        // 8-round extract-min merge (always writes exactly 8 valid entries)
        const unsigned long long SENT = ~0ull;
        unsigned long long k0 = SENT, k1 = SENT, k2 = SENT, k3 = SENT,
                           k4 = SENT, k5 = SENT, k6 = SENT, k7 = SENT;
        for (int k = 0; k < 36; ++k) {
            int j = lane + (k << 6);
            float2 fj = f[j];
            float h = __fmaf_rn(xi2, fj.x, __fmaf_rn(yi2, fj.y, sq[j]));
            if (k == k_i) h = (lane == lane_i) ? FLT_MAX : h;
            unsigned int bits = __float_as_uint(h);
            if (bits == 0x80000000u) bits = 0u;
            unsigned int s = bits ^ (unsigned int)(((int)bits >> 31) | 0x80000000);
            unsigned long long key = ((unsigned long long)s << 32) | (unsigned int)j;
            if (key < k7) {
                k7 = key;
                if (k7 < k6) { unsigned long long t = k6; k6 = k7; k7 = t; }
                if (k6 < k5) { unsigned long long t = k5; k5 = k6; k6 = t; }
                if (k5 < k4) { unsigned long long t = k4; k4 = k5; k5 = t; }
                if (k4 < k3) { unsigned long long t = k3; k3 = k4; k4 = t; }
                if (k3 < k2) { unsigned long long t = k2; k2 = k3; k3 = t; }
                if (k2 < k1) { unsigned long long t = k1; k1 = k2; k2 = t; }
                if (k1 < k0) { unsigned long long t = k0; k0 = k1; k1 = t; }
            }
        }
        unsigned long long mywin = 0;
        #pragma unroll
        for (int r = 0; r < KNN; ++r) {
            unsigned long long h = k0;
            #pragma unroll
            for (int off = 32; off > 0; off >>= 1) {
                unsigned long long o = __shfl_xor(h, off, 64);
                if (o < h) h = o;
            }
            if (lane == r) mywin = h;
            if (k0 == h) {
                k0 = k1; k1 = k2; k2 = k3; k3 = k4; k4 = k5; k5 = k6; k6 = k7; k7 = SENT;
            }
        }
        if (lane < KNN) {
            int j = (int)(unsigned int)(mywin & 0xFFFFFFFFull);
            idx[(b * MNODE + i) * KNN + lane] = j;
            atomicAdd(&cnt[b * MNODE + j], 1);
        }
    }
}

__global__ void dinv_kernel(const int* __restrict__ cnt, float* __restrict__ dinv) {
    int gid = blockIdx.x * blockDim.x + threadIdx.x;
    if (gid >= BM) return;
    float deg = (float)(KNN + cnt[gid]);
    dinv[gid] = 1.0f / sqrtf(deg + 1e-8f);
}

// exclusive prefix sum over cnt[BM] -> offs[BM]; single block of 256 threads
__global__ void __launch_bounds__(256) scan_kernel(const int* __restrict__ cnt,
                                                   int* __restrict__ offs) {
    __shared__ int part[256];
    int tid = threadIdx.x;
    const int per = BM / 256;   // 144
    int base = tid * per;
    int s = 0;
    for (int k = 0; k < per; ++k) s += cnt[base + k];
    part[tid] = s;
    __syncthreads();
    if (tid == 0) {
        int run = 0;
        for (int t = 0; t < 256; ++t) { int tmp = part[t]; part[t] = run; run += tmp; }
    }
    __syncthreads();
    int run = part[tid];
    for (int k = 0; k < per; ++k) { offs[base + k] = run; run += cnt[base + k]; }
}

// scatter each directed edge i->j into j's reverse list (int atomics for slots)
__global__ void fill_kernel(const int* __restrict__ idx, const int* __restrict__ offs,
                            int* __restrict__ fptr, int* __restrict__ rev) {
    int gid = blockIdx.x * blockDim.x + threadIdx.x;
    if (gid >= BM * KNN) return;
    int b = gid / (MNODE * KNN);
    int rem = gid - b * (MNODE * KNN);
    int i = rem / KNN;
    int gj = b * MNODE + idx[gid];
    int pos = atomicAdd(&fptr[gj], 1);
    rev[offs[gj] + pos] = b * MNODE + i;
}

// zA[i][c] = sum over neighbors j (both directions) with j%9==c of w_ij * S[j]
__global__ void __launch_bounds__(256) gather1_kernel(
    const int* __restrict__ idx, const int* __restrict__ offs, const int* __restrict__ cnt,
    const int* __restrict__ rev, const float* __restrict__ dinv, const float* __restrict__ S,
    float* __restrict__ zA) {
    int gi = blockIdx.x * blockDim.x + threadIdx.x;
    if (gi >= BM) return;
    int b = gi / MNODE;
    float acc[2 * CFREQ];
    #pragma unroll
    for (int k = 0; k < 2 * CFREQ; ++k) acc[k] = 0.0f;
    float di = dinv[gi] * 0.5f;   // fold ew/S_SCALE
    #pragma unroll
    for (int k = 0; k < KNN; ++k) {
        int gj = b * MNODE + idx[gi * KNN + k];
        float w = di * dinv[gj];
        int c = gj % CFREQ;
        acc[2 * c + 0] += w * S[gj * 2 + 0];
        acc[2 * c + 1] += w * S[gj * 2 + 1];
    }
    int o = offs[gi], e = o + cnt[gi];
    for (int p = o; p < e; ++p) {
        int gk = rev[p];
        float w = di * dinv[gk];
        int c = gk % CFREQ;
        acc[2 * c + 0] += w * S[gk * 2 + 0];
        acc[2 * c + 1] += w * S[gk * 2 + 1];
    }
    #pragma unroll
    for (int k = 0; k < 2 * CFREQ; ++k) zA[gi * 2 * CFREQ + k] = acc[k];
}

// zB[i][c] = sum over neighbors j (both directions) of w_ij * zA[j][c]
// 4 threads per row (c-quarters {0-2},{3-4},{5-6},{7-8}) for occupancy:
// the 1-thread-per-row version ran only 144 blocks (<1 wave/SIMD machine-wide).
__global__ void __launch_bounds__(256) gather2_kernel(
    const int* __restrict__ idx, const int* __restrict__ offs, const int* __restrict__ cnt,
    const int* __restrict__ rev, const float* __restrict__ dinv, const float* __restrict__ zA,
    float* __restrict__ zB) {
    int gid = blockIdx.x * blockDim.x + threadIdx.x;
    if (gid >= BM * 4) return;
    int gi = gid >> 2;
    int q = gid & 3;
    int c0 = (q == 0) ? 0 : (1 + 2 * q);          // 0,3,5,7
    int nc = (q == 0) ? 3 : 2;
    int b = gi / MNODE;
    float acc[6];
    #pragma unroll
    for (int k = 0; k < 6; ++k) acc[k] = 0.0f;
    float di = dinv[gi] * 0.5f;
    #pragma unroll
    for (int k = 0; k < KNN; ++k) {
        int gj = b * MNODE + idx[gi * KNN + k];
        float w = di * dinv[gj];
        const float2* za = (const float2*)(zA + gj * 2 * CFREQ) + c0;
        #pragma unroll
        for (int c = 0; c < 3; ++c) {
            if (c < nc) {
                float2 v = za[c];
                acc[2 * c + 0] += w * v.x;
                acc[2 * c + 1] += w * v.y;
            }
        }
    }
    int o = offs[gi], e = o + cnt[gi];
    for (int p = o; p < e; ++p) {
        int gk = rev[p];
        float w = di * dinv[gk];
        const float2* za = (const float2*)(zA + gk * 2 * CFREQ) + c0;
        #pragma unroll
        for (int c = 0; c < 3; ++c) {
            if (c < nc) {
                float2 v = za[c];
                acc[2 * c + 0] += w * v.x;
                acc[2 * c + 1] += w * v.y;
            }
        }
    }
    #pragma unroll
    for (int c = 0; c < 3; ++c) {
        if (c < nc) {
            zB[(gi * CFREQ + c0 + c) * 2 + 0] = acc[2 * c + 0];
            zB[(gi * CFREQ + c0 + c) * 2 + 1] = acc[2 * c + 1];
        }
    }
}

// FE[c,e] = freq_emb[c,:] @ (Wr + i Wi)^T  (9 x 128 complex)
__global__ void fe_kernel(const float* __restrict__ femb, const float* __restrict__ Wr,
                          const float* __restrict__ Wi, float* __restrict__ FE) {
    int gid = blockIdx.x * blockDim.x + threadIdx.x;
    if (gid >= CFREQ * EMBED) return;
    int c = gid / EMBED;
    int e = gid - c * EMBED;
    float ar = 0.0f, ai = 0.0f;
    for (int k = 0; k < EMBED; ++k) {
        float f = femb[c * EMBED + k];
        ar += f * Wr[e * EMBED + k];
        ai += f * Wi[e * EMBED + k];
    }
    FE[gid * 2 + 0] = ar;
    FE[gid * 2 + 1] = ai;
}

// per row r: z_acc (9 complex) -> u = z_acc . FE -> csilu -> eo projection (complex scalar)
__global__ void __launch_bounds__(256) rowproj_kernel(
    const float* __restrict__ S, const float* __restrict__ zA, const float* __restrict__ zB,
    const float* __restrict__ FE, const float* __restrict__ eoWr, const float* __restrict__ eoWi,
    const float* __restrict__ theta, const float* __restrict__ approx,
    float* __restrict__ Sout) {
    int wave = threadIdx.x >> 6;
    int lane = threadIdx.x & 63;
    int r = blockIdx.x * 4 + wave;
    if (r >= BM) return;
    float a0 = theta[0] * approx[0] + theta[1] * approx[3];
    float a1 = theta[0] * approx[1] + theta[1] * approx[4];
    float a2 = theta[0] * approx[2] + theta[1] * approx[5];
    float ca = a0 - a2, cb = -a1, cc = 2.0f * a2;
    int cr = r % CFREQ;
    float sr = S[r * 2 + 0], si = S[r * 2 + 1];
    int e1 = lane + 64;
    float ur0 = 0.0f, ui0 = 0.0f, ur1 = 0.0f, ui1 = 0.0f;
    #pragma unroll
    for (int c = 0; c < CFREQ; ++c) {
        float zr = cb * zA[(r * CFREQ + c) * 2 + 0] + cc * zB[(r * CFREQ + c) * 2 + 0];
        float zi = cb * zA[(r * CFREQ + c) * 2 + 1] + cc * zB[(r * CFREQ + c) * 2 + 1];
        if (c == cr) { zr += ca * sr; zi += ca * si; }
        float fr0 = FE[(c * EMBED + lane) * 2 + 0], fi0 = FE[(c * EMBED + lane) * 2 + 1];
        float fr1 = FE[(c * EMBED + e1) * 2 + 0],  fi1 = FE[(c * EMBED + e1) * 2 + 1];
        ur0 += zr * fr0 - zi * fi0;  ui0 += zr * fi0 + zi * fr0;
        ur1 += zr * fr1 - zi * fi1;  ui1 += zr * fi1 + zi * fr1;
    }
    float hr0 = silu_f(ur0), hi0 = silu_f(ui0);
    float hr1 = silu_f(ur1), hi1 = silu_f(ui1);
    float wr0 = eoWr[lane], wi0 = eoWi[lane], wr1 = eoWr[e1], wi1 = eoWi[e1];
    float p = hr0 * wr0 - hi0 * wi0 + hr1 * wr1 - hi1 * wi1;
    float q = hr0 * wi0 + hi0 * wr0 + hr1 * wi1 + hi1 * wr1;
    #pragma unroll
    for (int off = 32; off > 0; off >>= 1) {
        p += __shfl_down(p, off, 64);
        q += __shfl_down(q, off, 64);
    }
    if (lane == 0) {
        Sout[r * 2 + 0] = p;
        Sout[r * 2 + 1] = q;
    }
}

// per (b,n): irfft96 -> inorm+silu -> W1 -> inorm+silu -> W2 -> + trend_emb -> W3 -> out
__global__ void __launch_bounds__(128) head_kernel(
    const float* __restrict__ Sout, const float* __restrict__ trend,
    const float* __restrict__ n1w, const float* __restrict__ n1b,
    const float* __restrict__ n2w, const float* __restrict__ n2b,
    const float* __restrict__ W1w, const float* __restrict__ W1b,
    const float* __restrict__ W2w, const float* __restrict__ W2b,
    const float* __restrict__ Wtw, const float* __restrict__ Wtb,
    const float* __restrict__ W3w, const float* __restrict__ W3b,
    float* __restrict__ out) {
    __shared__ float tabc[96], tabs[96], hraw[96], sH[96], tbuf[96];
    __shared__ float srow[18], h2[64], s3[64], red[2];
    __shared__ float wbuf[6240];
    int bn = blockIdx.x;
    int b = bn >> 8;
    int n = bn & 255;
    int tid = threadIdx.x;
    if (tid < 96) {
        double a = 6.283185307179586476925286766559 * (double)tid / 96.0;
        tabc[tid] = (float)cos(a);
        tabs[tid] = (float)sin(a);
        tbuf[tid] = trend[b * TN + tid * NNODE + n];
    }
    if (tid < 18) srow[tid] = Sout[bn * 18 + tid];
    __syncthreads();
    float hv = 0.0f;
    if (tid < 96) {
        float acc = srow[0];   // Im(bin0) ignored by irfft
        #pragma unroll
        for (int c = 1; c < CFREQ; ++c) {
            int k = (c * tid) % 96;
            acc += 2.0f * (srow[2 * c] * tabc[k] - srow[2 * c + 1] * tabs[k]);
        }
        hv = acc * 0.10206207261596575f;  // 1/sqrt(96)
        hraw[tid] = hv;
    }
    __syncthreads();
    if (tid < 64) {
        float v = hraw[tid] + ((tid < 32) ? hraw[64 + tid] : 0.0f);
        #pragma unroll
        for (int off = 32; off > 0; off >>= 1) v += __shfl_down(v, off, 64);
        if (tid == 0) red[0] = v * (1.0f / 96.0f);
    }
    __syncthreads();
    float mu = red[0];
    if (tid < 64) {
        float d0 = hraw[tid] - mu;
        float v = d0 * d0;
        if (tid < 32) { float d1 = hraw[64 + tid] - mu; v += d1 * d1; }
        #pragma unroll
        for (int off = 32; off > 0; off >>= 1) v += __shfl_down(v, off, 64);
        if (tid == 0) red[1] = v * (1.0f / 96.0f);
    }
    __syncthreads();
    float var = red[1];
    if (tid < 96) {
        float xn = (hv - mu) / sqrtf(var + 1e-5f) * n1w[n] + n1b[n];
        sH[tid] = silu_f(xn);
    }
    for (int i = tid; i < HIDDEN * 96; i += 128) {
        int rr = i / 96;
        wbuf[rr * 97 + (i - rr * 96)] = W1w[i];
    }
    __syncthreads();
    float v1 = 0.0f;
    if (tid < 64) {
        float acc = W1b[tid];
        #pragma unroll 8
        for (int t = 0; t < 96; ++t) acc += sH[t] * wbuf[tid * 97 + t];
        v1 = acc;
    }
    if (tid < 64) {
        float s = v1;
        #pragma unroll
        for (int off = 32; off > 0; off >>= 1) s += __shfl_down(s, off, 64);
        s = __shfl(s, 0, 64);
        float mu2 = s * (1.0f / 64.0f);
        float d = v1 - mu2;
        float vs = d * d;
        #pragma unroll
        for (int off = 32; off > 0; off >>= 1) vs += __shfl_down(vs, off, 64);
        vs = __shfl(vs, 0, 64);
        float var2 = vs * (1.0f / 64.0f);
        float xn = (v1 - mu2) / sqrtf(var2 + 1e-5f) * n2w[n] + n2b[n];
        h2[tid] = silu_f(xn);
    }
    __syncthreads();   // wbuf(W1) reads + h2 writes done
    for (int i = tid; i < HIDDEN * HIDDEN; i += 128) {
        wbuf[(i >> 6) * 65 + (i & 63)] = W2w[i];
    }
    __syncthreads();
    float v3 = 0.0f;
    if (tid < 64) {
        float acc = W2b[tid];
        #pragma unroll 8
        for (int h = 0; h < 64; ++h) acc += h2[h] * wbuf[tid * 65 + h];
        v3 = acc;
    }
    __syncthreads();   // wbuf(W2) reads done
    for (int i = tid; i < HIDDEN * 96; i += 128) {
        int rr = i / 96;
        wbuf[rr * 97 + (i - rr * 96)] = Wtw[i];
    }
    __syncthreads();
    if (tid < 64) {
        float acc = Wtb[tid];
        #pragma unroll 8
        for (int t = 0; t < 96; ++t) acc += tbuf[t] * wbuf[tid * 97 + t];
        s3[tid] = v3 + acc;
    }
    __syncthreads();   // wbuf(Wt) reads + s3 writes done
    for (int i = tid; i < 96 * HIDDEN; i += 128) {
        wbuf[(i >> 6) * 65 + (i & 63)] = W3w[i];
    }
    __syncthreads();
    if (tid < 96) {
        float acc = W3b[tid];
        #pragma unroll 8
        for (int h = 0; h < 64; ++h) acc += s3[h] * wbuf[tid * 65 + h];
        out[bn * 96 + tid] = acc;
    }
}

extern "C" void kernel_launch(void* const* d_in, const int* in_sizes, int n_in,
                              void* d_out, int out_size, void* d_ws, size_t ws_size,
                              hipStream_t stream) {
    const float* x     = (const float*)d_in[0];
    const float* approx= (const float*)d_in[1];
    const float* theta = (const float*)d_in[2];
    const float* frWr  = (const float*)d_in[3];
    const float* frWi  = (const float*)d_in[4];
    const float* eoWr  = (const float*)d_in[5];
    const float* eoWi  = (const float*)d_in[6];
    const float* femb  = (const float*)d_in[7];
    const float* n1w   = (const float*)d_in[8];
    const float* n1b   = (const float*)d_in[9];
    const float* n2w   = (const float*)d_in[10];
    const float* n2b   = (const float*)d_in[11];
    const float* W1w   = (const float*)d_in[12];
    const float* W1b   = (const float*)d_in[13];
    const float* W2w   = (const float*)d_in[14];
    const float* W2b   = (const float*)d_in[15];
    const float* Wtw   = (const float*)d_in[16];
    const float* Wtb   = (const float*)d_in[17];
    const float* W3w   = (const float*)d_in[18];
    const float* W3b   = (const float*)d_in[19];
    float* out = (float*)d_out;

    char* ws = (char*)d_ws;
    size_t off = 0;
    auto alloc = [&](size_t bytes) -> void* {
        void* p = ws + off;
        off = (off + bytes + 255) & ~(size_t)255;
        return p;
    };
    float* trend = (float*)alloc((size_t)BATCH * TN * 4);
    float* S     = (float*)alloc((size_t)BM * 2 * 4);
    int*   idx   = (int*)  alloc((size_t)BM * KNN * 4);
    float* dinv  = (float*)alloc((size_t)BM * 4);
    float* FE    = (float*)alloc((size_t)CFREQ * EMBED * 2 * 4);
    float* Sout  = (float*)alloc((size_t)BM * 2 * 4);
    int*   offs  = (int*)  alloc((size_t)BM * 4);
    int*   rev   = (int*)  alloc((size_t)BM * KNN * 4);
    float* zA    = (float*)alloc((size_t)BM * CFREQ * 2 * 4);
    float* zB    = (float*)alloc((size_t)BM * CFREQ * 2 * 4);
    char*  zbase = ws + off;
    int*   cnt   = (int*)  alloc((size_t)BM * 4);
    int*   fptr  = (int*)  alloc((size_t)BM * 4);
    size_t zbytes = (size_t)(ws + off - zbase);

    hipMemsetAsync(zbase, 0, zbytes, stream);   // cnt + fptr only (288 KB)

    trend_kernel<<<(BATCH * TN + 255) / 256, 256, 0, stream>>>(x, trend);
    fft_kernel<<<(BM + 255) / 256, 256, 0, stream>>>(x, trend, S);
    knn_kernel<<<dim3(MNODE / 4, BATCH), 256, 0, stream>>>(S, idx, cnt);
    dinv_kernel<<<(BM + 255) / 256, 256, 0, stream>>>(cnt, dinv);
    scan_kernel<<<1, 256, 0, stream>>>(cnt, offs);
    fill_kernel<<<(BM * KNN + 255) / 256, 256, 0, stream>>>(idx, offs, fptr, rev);
    gather1_kernel<<<(BM + 255) / 256, 256, 0, stream>>>(idx, offs, cnt, rev, dinv, S, zA);
    gather2_kernel<<<(BM * 4 + 255) / 256, 256, 0, stream>>>(idx, offs, cnt, rev, dinv, zA, zB);
    fe_kernel<<<(CFREQ * EMBED + 255) / 256, 256, 0, stream>>>(femb, frWr, frWi, FE);
    rowproj_kernel<<<BM / 4, 256, 0, stream>>>(S, zA, zB, FE, eoWr, eoWi, theta, approx, Sout);
    head_kernel<<<BATCH * NNODE, 128, 0, stream>>>(Sout, trend, n1w, n1b, n2w, n2b,
                                                   W1w, W1b, W2w, W2b, Wtw, Wtb, W3w, W3b, out);
}

// Round 5
// 328.926 us; speedup vs baseline: 1.0633x; 1.0633x over previous
//
#include <hip/hip_runtime.h>
#include <math.h>
#include <float.h>

#define BATCH 16
#define SEQ 96
#define NNODE 256
#define CFREQ 9
#define MNODE (NNODE * CFREQ)      // 2304
#define BM (BATCH * MNODE)         // 36864
#define KNN 8
#define EMBED 128
#define HIDDEN 64
#define TN (SEQ * NNODE)           // 24576
#define KCAP 64
#define NBLK (BM / 256)            // 144 scan blocks

__constant__ float COS16[16] = {
    1.0f, 0.9238795325112867f, 0.7071067811865476f, 0.3826834323650898f,
    0.0f, -0.3826834323650898f, -0.7071067811865476f, -0.9238795325112867f,
    -1.0f, -0.9238795325112867f, -0.7071067811865476f, -0.3826834323650898f,
    0.0f, 0.3826834323650898f, 0.7071067811865476f, 0.9238795325112867f};
__constant__ float SIN16[16] = {
    0.0f, 0.3826834323650898f, 0.7071067811865476f, 0.9238795325112867f,
    1.0f, 0.9238795325112867f, 0.7071067811865476f, 0.3826834323650898f,
    0.0f, -0.3826834323650898f, -0.7071067811865476f, -0.9238795325112867f,
    -1.0f, -0.9238795325112867f, -0.7071067811865476f, -0.3826834323650898f};

static __device__ __forceinline__ float silu_f(float x) {
    return x / (1.0f + expf(-x));
}

// ranking value h = |fj|^2 - 2*(fi . fj); bit-identical across P1/P2/fallback
static __device__ __forceinline__ float rank_h(float2 fj, float xi2, float yi2) {
    float sqj = __fmaf_rn(fj.y, fj.y, __fmul_rn(fj.x, fj.x));
    return __fmaf_rn(xi2, fj.x, __fmaf_rn(yi2, fj.y, sqj));
}

// trend[b,t,n] = (x[t-1]+x[t]+x[t+1])/3 with edge clamp; layout (B,T,N)
__global__ void trend_kernel(const float* __restrict__ x, float* __restrict__ trend) {
    int gid = blockIdx.x * blockDim.x + threadIdx.x;
    if (gid >= BATCH * TN) return;
    int b = gid / TN;
    int rem = gid - b * TN;
    int t = rem / NNODE;
    int n = rem - t * NNODE;
    int tm = t > 0 ? t - 1 : 0;
    int tp = t < SEQ - 1 ? t + 1 : SEQ - 1;
    const float* xb = x + b * TN;
    float v = (xb[tm * NNODE + n] + xb[t * NNODE + n] + xb[tp * NNODE + n]) * (1.0f / 3.0f);
    trend[gid] = v;
}

// S[b, m] = ortho-rfft16 of (x - trend) over first 16 t; m = n*9 + c
__global__ void fft_kernel(const float* __restrict__ x, const float* __restrict__ trend,
                           float* __restrict__ S) {
    int gid = blockIdx.x * blockDim.x + threadIdx.x;
    if (gid >= BM) return;
    int b = gid / MNODE;
    int m = gid - b * MNODE;
    int n = m / CFREQ;
    int c = m - n * CFREQ;
    const float* xb = x + b * TN + n;
    const float* tb = trend + b * TN + n;
    float re = 0.0f, im = 0.0f;
    #pragma unroll
    for (int t = 0; t < 16; ++t) {
        float s = xb[t * NNODE] - tb[t * NNODE];
        int k = (c * t) & 15;
        re += s * COS16[k];
        im -= s * SIN16[k];
    }
    S[gid * 2 + 0] = re * 0.25f;
    S[gid * 2 + 1] = im * 0.25f;
}

// One WAVE per row, 4 rows per 256-block. Exact top-8.
// Round-3-proven structure (ballot-prefix compaction, no sq LDS, 20480B LDS,
// 8 blocks/CU) + round-4-proven cheap math (h ranking, scalar self-exclusion).
//  P1: streaming per-lane min of h over 36 candidates (4 VALU/eval).
//  T : max over 8 disjoint 8-lane groups of group-min of lane minima
//      (6 shuffles). >=8 candidates have h <= T => T >= true h8.
//  P2: recompute h (bit-identical), ballot/popcll-prefix append of survivor
//      u64 keys (sortable_h | j) into wave-private LDS buffer. No atomics,
//      no barrier (same-wave DS ops are in-order).
//  P3 (guarded: KNN <= total <= KCAP): rank selection via broadcast reads;
//      unique keys -> unique ranks 0..7, initialized slots only.
//  Else: exact full-scan fallback (insert network + 8-round extract-min).
__global__ void __launch_bounds__(256, 8) knn_kernel(const float* __restrict__ S,
                                                     int* __restrict__ idx, int* __restrict__ cnt) {
    __shared__ float2 f[MNODE];                        // 18432 B
    __shared__ unsigned long long kbuf[4][KCAP];       // 2048 B -> total 20480 = 160K/8
    int b = blockIdx.y;
    int tid = threadIdx.x;
    for (int t = tid; t < MNODE; t += 256) {
        f[t] = make_float2(S[(b * MNODE + t) * 2 + 0], S[(b * MNODE + t) * 2 + 1]);
    }
    __syncthreads();
    int wave = tid >> 6, lane = tid & 63;
    int i = blockIdx.x * 4 + wave;
    float2 fi = f[i];
    float xi2 = __fmul_rn(-2.0f, fi.x), yi2 = __fmul_rn(-2.0f, fi.y);
    int lane_i = __builtin_amdgcn_readfirstlane(i & 63);
    int k_i    = __builtin_amdgcn_readfirstlane(i >> 6);

    // Phase 1: per-lane min of h over 36 candidates (streaming)
    float mymin = FLT_MAX;
    #pragma unroll 12
    for (int k = 0; k < 36; ++k) {
        int j = lane + (k << 6);
        float h = rank_h(f[j], xi2, yi2);
        if (k == k_i) h = (lane == lane_i) ? FLT_MAX : h;
        mymin = fminf(mymin, h);
    }
    // Threshold: 6 dependent shuffles. Group-min (lanes differing in bits 0-2),
    // then max across the 8 groups (bits 3-5).
    float g = mymin;
    g = fminf(g, __shfl_xor(g, 1, 64));
    g = fminf(g, __shfl_xor(g, 2, 64));
    g = fminf(g, __shfl_xor(g, 4, 64));
    float T = g;
    T = fmaxf(T, __shfl_xor(T, 8, 64));
    T = fmaxf(T, __shfl_xor(T, 16, 64));
    T = fmaxf(T, __shfl_xor(T, 32, 64));
    // Phase 2: recompute h + ballot-compacted append of survivors' exact keys
    unsigned long long* mybuf = kbuf[wave];
    int total = 0;
    #pragma unroll 12
    for (int k = 0; k < 36; ++k) {
        int j = lane + (k << 6);
        float h = rank_h(f[j], xi2, yi2);
        if (k == k_i) h = (lane == lane_i) ? FLT_MAX : h;
        bool pred = h <= T;
        unsigned long long mask = __ballot(pred);
        if (pred) {
            int pos = total + (int)__popcll(mask & ((1ull << lane) - 1ull));
            if (pos < KCAP) {
                unsigned int bits = __float_as_uint(h);
                if (bits == 0x80000000u) bits = 0u;
                unsigned int s = bits ^ (unsigned int)(((int)bits >> 31) | 0x80000000);
                mybuf[pos] = ((unsigned long long)s << 32) | (unsigned int)j;
            }
        }
        total += (int)__popcll(mask);
    }
    // no block barrier: kbuf[wave] is wave-private; same-wave DS ops in-order

    if (total >= KNN && total <= KCAP) {
        // Phase 3: rank selection over the survivor list (broadcast reads)
        for (int p = lane; p < total; p += 64) {
            unsigned long long mykey = mybuf[p];
            int rank = 0;
            for (int q = 0; q < total; ++q) {
                rank += (mybuf[q] < mykey) ? 1 : 0;
            }
            if (rank < KNN) {
                int j = (int)(unsigned int)(mykey & 0xFFFFFFFFull);
                idx[(b * MNODE + i) * KNN + rank] = j;
                atomicAdd(&cnt[b * MNODE + j], 1);
            }
        }
    } else {
        // exact fallback: full recompute scan, per-lane insert network +
        // 8-round extract-min merge (always writes exactly 8 valid entries)
        const unsigned long long SENT = ~0ull;
        unsigned long long k0 = SENT, k1 = SENT, k2 = SENT, k3 = SENT,
                           k4 = SENT, k5 = SENT, k6 = SENT, k7 = SENT;
        for (int k = 0; k < 36; ++k) {
            int j = lane + (k << 6);
            float h = rank_h(f[j], xi2, yi2);
            if (k == k_i) h = (lane == lane_i) ? FLT_MAX : h;
            unsigned int bits = __float_as_uint(h);
            if (bits == 0x80000000u) bits = 0u;
            unsigned int s = bits ^ (unsigned int)(((int)bits >> 31) | 0x80000000);
            unsigned long long key = ((unsigned long long)s << 32) | (unsigned int)j;
            if (key < k7) {
                k7 = key;
                if (k7 < k6) { unsigned long long t = k6; k6 = k7; k7 = t; }
                if (k6 < k5) { unsigned long long t = k5; k5 = k6; k6 = t; }
                if (k5 < k4) { unsigned long long t = k4; k4 = k5; k5 = t; }
                if (k4 < k3) { unsigned long long t = k3; k3 = k4; k4 = t; }
                if (k3 < k2) { unsigned long long t = k2; k2 = k3; k3 = t; }
                if (k2 < k1) { unsigned long long t = k1; k1 = k2; k2 = t; }
                if (k1 < k0) { unsigned long long t = k0; k0 = k1; k1 = t; }
            }
        }
        unsigned long long mywin = 0;
        #pragma unroll
        for (int r = 0; r < KNN; ++r) {
            unsigned long long hh = k0;
            #pragma unroll
            for (int off = 32; off > 0; off >>= 1) {
                unsigned long long o = __shfl_xor(hh, off, 64);
                if (o < hh) hh = o;
            }
            if (lane == r) mywin = hh;
            if (k0 == hh) {
                k0 = k1; k1 = k2; k2 = k3; k3 = k4; k4 = k5; k5 = k6; k6 = k7; k7 = SENT;
            }
        }
        if (lane < KNN) {
            int j = (int)(unsigned int)(mywin & 0xFFFFFFFFull);
            idx[(b * MNODE + i) * KNN + lane] = j;
            atomicAdd(&cnt[b * MNODE + j], 1);
        }
    }
}

// dinv[j] = 1/sqrt(deg+eps); PS[j] = dinv[j] * S[j]  (pre-folded for gather1)
__global__ void dinv_kernel(const int* __restrict__ cnt, const float* __restrict__ S,
                            float* __restrict__ dinv, float* __restrict__ PS) {
    int gid = blockIdx.x * blockDim.x + threadIdx.x;
    if (gid >= BM) return;
    float deg = (float)(KNN + cnt[gid]);
    float dv = 1.0f / sqrtf(deg + 1e-8f);
    dinv[gid] = dv;
    PS[gid * 2 + 0] = dv * S[gid * 2 + 0];
    PS[gid * 2 + 1] = dv * S[gid * 2 + 1];
}

// --- coalesced 3-stage exclusive scan over cnt[BM] -> offs[BM] ---
// stage A: per-block (256 elems, coalesced) sums
__global__ void __launch_bounds__(256) scan_block_kernel(const int* __restrict__ cnt,
                                                         int* __restrict__ bsum) {
    __shared__ int wsum[4];
    int tid = threadIdx.x;
    int v = cnt[blockIdx.x * 256 + tid];
    int s = v;
    #pragma unroll
    for (int off = 32; off > 0; off >>= 1) s += __shfl_down(s, off, 64);
    if ((tid & 63) == 0) wsum[tid >> 6] = s;
    __syncthreads();
    if (tid == 0) bsum[blockIdx.x] = wsum[0] + wsum[1] + wsum[2] + wsum[3];
}
// stage B: exclusive scan of the 144 block sums (tiny, LDS-serial)
__global__ void __launch_bounds__(256) scan_top_kernel(const int* __restrict__ bsum,
                                                       int* __restrict__ bofs) {
    __shared__ int buf[NBLK];
    int tid = threadIdx.x;
    if (tid < NBLK) buf[tid] = bsum[tid];
    __syncthreads();
    if (tid == 0) {
        int run = 0;
        for (int t = 0; t < NBLK; ++t) { int v = buf[t]; buf[t] = run; run += v; }
    }
    __syncthreads();
    if (tid < NBLK) bofs[tid] = buf[tid];
}
// stage C: per-block exclusive prefix (wave shfl_up scan) + block offset
__global__ void __launch_bounds__(256) scan_apply_kernel(const int* __restrict__ cnt,
                                                         const int* __restrict__ bofs,
                                                         int* __restrict__ offs) {
    __shared__ int wsum[4];
    int tid = threadIdx.x;
    int gid = blockIdx.x * 256 + tid;
    int lane = tid & 63, wv = tid >> 6;
    int v = cnt[gid];
    int x = v;
    #pragma unroll
    for (int off = 1; off < 64; off <<= 1) {
        int y = __shfl_up(x, off, 64);
        if (lane >= off) x += y;
    }
    if (lane == 63) wsum[wv] = x;
    __syncthreads();
    int base = bofs[blockIdx.x];
    for (int w = 0; w < wv; ++w) base += wsum[w];
    offs[gid] = base + x - v;
}

// scatter each directed edge i->j into j's reverse list (int atomics for slots)
__global__ void fill_kernel(const int* __restrict__ idx, const int* __restrict__ offs,
                            int* __restrict__ fptr, int* __restrict__ rev) {
    int gid = blockIdx.x * blockDim.x + threadIdx.x;
    if (gid >= BM * KNN) return;
    int b = gid / (MNODE * KNN);
    int rem = gid - b * (MNODE * KNN);
    int i = rem / KNN;
    int gj = b * MNODE + idx[gid];
    int pos = atomicAdd(&fptr[gj], 1);
    rev[offs[gj] + pos] = b * MNODE + i;
}

// zA[i][c] = 0.5*dinv[i] * sum over neighbors j (both directions) with j%9==c of PS[j]
// 4 threads per row (c-quarters {0-2},{3-4},{5-6},{7-8}); static 6-float acc
// (the old runtime-indexed acc[18] was a scratch allocation - rule #20).
__global__ void __launch_bounds__(256) gather1_kernel(
    const int* __restrict__ idx, const int* __restrict__ offs, const int* __restrict__ cnt,
    const int* __restrict__ rev, const float* __restrict__ dinv, const float* __restrict__ PS,
    float* __restrict__ zA) {
    int gid = blockIdx.x * blockDim.x + threadIdx.x;
    if (gid >= BM * 4) return;
    int gi = gid >> 2;
    int q = gid & 3;
    int c0 = (q == 0) ? 0 : (1 + 2 * q);          // 0,3,5,7
    int nc = (q == 0) ? 3 : 2;
    int b = gi / MNODE;
    float a0 = 0.0f, a1 = 0.0f, a2 = 0.0f, a3 = 0.0f, a4 = 0.0f, a5 = 0.0f;
    #pragma unroll
    for (int k = 0; k < KNN; ++k) {
        int gj = b * MNODE + idx[gi * KNN + k];
        int rel = gj % CFREQ - c0;
        float2 p = ((const float2*)PS)[gj];
        bool t0 = (rel == 0), t1 = (rel == 1), t2 = (rel == 2) && (nc == 3);
        a0 += t0 ? p.x : 0.0f;  a1 += t0 ? p.y : 0.0f;
        a2 += t1 ? p.x : 0.0f;  a3 += t1 ? p.y : 0.0f;
        a4 += t2 ? p.x : 0.0f;  a5 += t2 ? p.y : 0.0f;
    }
    int o = offs[gi], e = o + cnt[gi];
    for (int p_ = o; p_ < e; ++p_) {
        int gk = rev[p_];
        int rel = gk % CFREQ - c0;
        float2 p = ((const float2*)PS)[gk];
        bool t0 = (rel == 0), t1 = (rel == 1), t2 = (rel == 2) && (nc == 3);
        a0 += t0 ? p.x : 0.0f;  a1 += t0 ? p.y : 0.0f;
        a2 += t1 ? p.x : 0.0f;  a3 += t1 ? p.y : 0.0f;
        a4 += t2 ? p.x : 0.0f;  a5 += t2 ? p.y : 0.0f;
    }
    float s = dinv[gi] * 0.5f;
    zA[(gi * CFREQ + c0 + 0) * 2 + 0] = s * a0;
    zA[(gi * CFREQ + c0 + 0) * 2 + 1] = s * a1;
    zA[(gi * CFREQ + c0 + 1) * 2 + 0] = s * a2;
    zA[(gi * CFREQ + c0 + 1) * 2 + 1] = s * a3;
    if (nc == 3) {
        zA[(gi * CFREQ + c0 + 2) * 2 + 0] = s * a4;
        zA[(gi * CFREQ + c0 + 2) * 2 + 1] = s * a5;
    }
}

// zB[i][c] = sum over neighbors j (both directions) of w_ij * zA[j][c]
// 4 threads per row (c-quarters) for occupancy.
__global__ void __launch_bounds__(256) gather2_kernel(
    const int* __restrict__ idx, const int* __restrict__ offs, const int* __restrict__ cnt,
    const int* __restrict__ rev, const float* __restrict__ dinv, const float* __restrict__ zA,
    float* __restrict__ zB) {
    int gid = blockIdx.x * blockDim.x + threadIdx.x;
    if (gid >= BM * 4) return;
    int gi = gid >> 2;
    int q = gid & 3;
    int c0 = (q == 0) ? 0 : (1 + 2 * q);          // 0,3,5,7
    int nc = (q == 0) ? 3 : 2;
    int b = gi / MNODE;
    float acc[6];
    #pragma unroll
    for (int k = 0; k < 6; ++k) acc[k] = 0.0f;
    float di = dinv[gi] * 0.5f;
    #pragma unroll
    for (int k = 0; k < KNN; ++k) {
        int gj = b * MNODE + idx[gi * KNN + k];
        float w = di * dinv[gj];
        const float2* za = (const float2*)(zA + gj * 2 * CFREQ) + c0;
        #pragma unroll
        for (int c = 0; c < 3; ++c) {
            if (c < nc) {
                float2 v = za[c];
                acc[2 * c + 0] += w * v.x;
                acc[2 * c + 1] += w * v.y;
            }
        }
    }
    int o = offs[gi], e = o + cnt[gi];
    for (int p = o; p < e; ++p) {
        int gk = rev[p];
        float w = di * dinv[gk];
        const float2* za = (const float2*)(zA + gk * 2 * CFREQ) + c0;
        #pragma unroll
        for (int c = 0; c < 3; ++c) {
            if (c < nc) {
                float2 v = za[c];
                acc[2 * c + 0] += w * v.x;
                acc[2 * c + 1] += w * v.y;
            }
        }
    }
    #pragma unroll
    for (int c = 0; c < 3; ++c) {
        if (c < nc) {
            zB[(gi * CFREQ + c0 + c) * 2 + 0] = acc[2 * c + 0];
            zB[(gi * CFREQ + c0 + c) * 2 + 1] = acc[2 * c + 1];
        }
    }
}

// FE[c,e] = freq_emb[c,:] @ (Wr + i Wi)^T  (9 x 128 complex)
__global__ void fe_kernel(const float* __restrict__ femb, const float* __restrict__ Wr,
                          const float* __restrict__ Wi, float* __restrict__ FE) {
    int gid = blockIdx.x * blockDim.x + threadIdx.x;
    if (gid >= CFREQ * EMBED) return;
    int c = gid / EMBED;
    int e = gid - c * EMBED;
    float ar = 0.0f, ai = 0.0f;
    for (int k = 0; k < EMBED; ++k) {
        float f = femb[c * EMBED + k];
        ar += f * Wr[e * EMBED + k];
        ai += f * Wi[e * EMBED + k];
    }
    FE[gid * 2 + 0] = ar;
    FE[gid * 2 + 1] = ai;
}

// per row r: z_acc (9 complex) -> u = z_acc . FE -> csilu -> eo projection (complex scalar)
__global__ void __launch_bounds__(256) rowproj_kernel(
    const float* __restrict__ S, const float* __restrict__ zA, const float* __restrict__ zB,
    const float* __restrict__ FE, const float* __restrict__ eoWr, const float* __restrict__ eoWi,
    const float* __restrict__ theta, const float* __restrict__ approx,
    float* __restrict__ Sout) {
    int wave = threadIdx.x >> 6;
    int lane = threadIdx.x & 63;
    int r = blockIdx.x * 4 + wave;
    if (r >= BM) return;
    float a0 = theta[0] * approx[0] + theta[1] * approx[3];
    float a1 = theta[0] * approx[1] + theta[1] * approx[4];
    float a2 = theta[0] * approx[2] + theta[1] * approx[5];
    float ca = a0 - a2, cb = -a1, cc = 2.0f * a2;
    int cr = r % CFREQ;
    float sr = S[r * 2 + 0], si = S[r * 2 + 1];
    int e1 = lane + 64;
    float ur0 = 0.0f, ui0 = 0.0f, ur1 = 0.0f, ui1 = 0.0f;
    #pragma unroll
    for (int c = 0; c < CFREQ; ++c) {
        float zr = cb * zA[(r * CFREQ + c) * 2 + 0] + cc * zB[(r * CFREQ + c) * 2 + 0];
        float zi = cb * zA[(r * CFREQ + c) * 2 + 1] + cc * zB[(r * CFREQ + c) * 2 + 1];
        if (c == cr) { zr += ca * sr; zi += ca * si; }
        float fr0 = FE[(c * EMBED + lane) * 2 + 0], fi0 = FE[(c * EMBED + lane) * 2 + 1];
        float fr1 = FE[(c * EMBED + e1) * 2 + 0],  fi1 = FE[(c * EMBED + e1) * 2 + 1];
        ur0 += zr * fr0 - zi * fi0;  ui0 += zr * fi0 + zi * fr0;
        ur1 += zr * fr1 - zi * fi1;  ui1 += zr * fi1 + zi * fr1;
    }
    float hr0 = silu_f(ur0), hi0 = silu_f(ui0);
    float hr1 = silu_f(ur1), hi1 = silu_f(ui1);
    float wr0 = eoWr[lane], wi0 = eoWi[lane], wr1 = eoWr[e1], wi1 = eoWi[e1];
    float p = hr0 * wr0 - hi0 * wi0 + hr1 * wr1 - hi1 * wi1;
    float q = hr0 * wi0 + hi0 * wr0 + hr1 * wi1 + hi1 * wr1;
    #pragma unroll
    for (int off = 32; off > 0; off >>= 1) {
        p += __shfl_down(p, off, 64);
        q += __shfl_down(q, off, 64);
    }
    if (lane == 0) {
        Sout[r * 2 + 0] = p;
        Sout[r * 2 + 1] = q;
    }
}

// per (b,n): irfft96 -> inorm+silu -> W1 -> inorm+silu -> W2 -> + trend_emb -> W3 -> out
__global__ void __launch_bounds__(128) head_kernel(
    const float* __restrict__ Sout, const float* __restrict__ trend,
    const float* __restrict__ n1w, const float* __restrict__ n1b,
    const float* __restrict__ n2w, const float* __restrict__ n2b,
    const float* __restrict__ W1w, const float* __restrict__ W1b,
    const float* __restrict__ W2w, const float* __restrict__ W2b,
    const float* __restrict__ Wtw, const float* __restrict__ Wtb,
    const float* __restrict__ W3w, const float* __restrict__ W3b,
    float* __restrict__ out) {
    __shared__ float tabc[96], tabs[96], hraw[96], sH[96], tbuf[96];
    __shared__ float srow[18], h2[64], s3[64], red[2];
    __shared__ float wbuf[6240];
    int bn = blockIdx.x;
    int b = bn >> 8;
    int n = bn & 255;
    int tid = threadIdx.x;
    if (tid < 96) {
        double a = 6.283185307179586476925286766559 * (double)tid / 96.0;
        tabc[tid] = (float)cos(a);
        tabs[tid] = (float)sin(a);
        tbuf[tid] = trend[b * TN + tid * NNODE + n];
    }
    if (tid < 18) srow[tid] = Sout[bn * 18 + tid];
    __syncthreads();
    float hv = 0.0f;
    if (tid < 96) {
        float acc = srow[0];   // Im(bin0) ignored by irfft
        #pragma unroll
        for (int c = 1; c < CFREQ; ++c) {
            int k = (c * tid) % 96;
            acc += 2.0f * (srow[2 * c] * tabc[k] - srow[2 * c + 1] * tabs[k]);
        }
        hv = acc * 0.10206207261596575f;  // 1/sqrt(96)
        hraw[tid] = hv;
    }
    __syncthreads();
    if (tid < 64) {
        float v = hraw[tid] + ((tid < 32) ? hraw[64 + tid] : 0.0f);
        #pragma unroll
        for (int off = 32; off > 0; off >>= 1) v += __shfl_down(v, off, 64);
        if (tid == 0) red[0] = v * (1.0f / 96.0f);
    }
    __syncthreads();
    float mu = red[0];
    if (tid < 64) {
        float d0 = hraw[tid] - mu;
        float v = d0 * d0;
        if (tid < 32) { float d1 = hraw[64 + tid] - mu; v += d1 * d1; }
        #pragma unroll
        for (int off = 32; off > 0; off >>= 1) v += __shfl_down(v, off, 64);
        if (tid == 0) red[1] = v * (1.0f / 96.0f);
    }
    __syncthreads();
    float var = red[1];
    if (tid < 96) {
        float xn = (hv - mu) / sqrtf(var + 1e-5f) * n1w[n] + n1b[n];
        sH[tid] = silu_f(xn);
    }
    for (int i = tid; i < HIDDEN * 96; i += 128) {
        int rr = i / 96;
        wbuf[rr * 97 + (i - rr * 96)] = W1w[i];
    }
    __syncthreads();
    float v1 = 0.0f;
    if (tid < 64) {
        float acc = W1b[tid];
        #pragma unroll 8
        for (int t = 0; t < 96; ++t) acc += sH[t] * wbuf[tid * 97 + t];
        v1 = acc;
    }
    if (tid < 64) {
        float s = v1;
        #pragma unroll
        for (int off = 32; off > 0; off >>= 1) s += __shfl_down(s, off, 64);
        s = __shfl(s, 0, 64);
        float mu2 = s * (1.0f / 64.0f);
        float d = v1 - mu2;
        float vs = d * d;
        #pragma unroll
        for (int off = 32; off > 0; off >>= 1) vs += __shfl_down(vs, off, 64);
        vs = __shfl(vs, 0, 64);
        float var2 = vs * (1.0f / 64.0f);
        float xn = (v1 - mu2) / sqrtf(var2 + 1e-5f) * n2w[n] + n2b[n];
        h2[tid] = silu_f(xn);
    }
    __syncthreads();   // wbuf(W1) reads + h2 writes done
    for (int i = tid; i < HIDDEN * HIDDEN; i += 128) {
        wbuf[(i >> 6) * 65 + (i & 63)] = W2w[i];
    }
    __syncthreads();
    float v3 = 0.0f;
    if (tid < 64) {
        float acc = W2b[tid];
        #pragma unroll 8
        for (int h = 0; h < 64; ++h) acc += h2[h] * wbuf[tid * 65 + h];
        v3 = acc;
    }
    __syncthreads();   // wbuf(W2) reads done
    for (int i = tid; i < HIDDEN * 96; i += 128) {
        int rr = i / 96;
        wbuf[rr * 97 + (i - rr * 96)] = Wtw[i];
    }
    __syncthreads();
    if (tid < 64) {
        float acc = Wtb[tid];
        #pragma unroll 8
        for (int t = 0; t < 96; ++t) acc += tbuf[t] * wbuf[tid * 97 + t];
        s3[tid] = v3 + acc;
    }
    __syncthreads();   // wbuf(Wt) reads + s3 writes done
    for (int i = tid; i < 96 * HIDDEN; i += 128) {
        wbuf[(i >> 6) * 65 + (i & 63)] = W3w[i];
    }
    __syncthreads();
    if (tid < 96) {
        float acc = W3b[tid];
        #pragma unroll 8
        for (int h = 0; h < 64; ++h) acc += s3[h] * wbuf[tid * 65 + h];
        out[bn * 96 + tid] = acc;
    }
}

extern "C" void kernel_launch(void* const* d_in, const int* in_sizes, int n_in,
                              void* d_out, int out_size, void* d_ws, size_t ws_size,
                              hipStream_t stream) {
    const float* x     = (const float*)d_in[0];
    const float* approx= (const float*)d_in[1];
    const float* theta = (const float*)d_in[2];
    const float* frWr  = (const float*)d_in[3];
    const float* frWi  = (const float*)d_in[4];
    const float* eoWr  = (const float*)d_in[5];
    const float* eoWi  = (const float*)d_in[6];
    const float* femb  = (const float*)d_in[7];
    const float* n1w   = (const float*)d_in[8];
    const float* n1b   = (const float*)d_in[9];
    const float* n2w   = (const float*)d_in[10];
    const float* n2b   = (const float*)d_in[11];
    const float* W1w   = (const float*)d_in[12];
    const float* W1b   = (const float*)d_in[13];
    const float* W2w   = (const float*)d_in[14];
    const float* W2b   = (const float*)d_in[15];
    const float* Wtw   = (const float*)d_in[16];
    const float* Wtb   = (const float*)d_in[17];
    const float* W3w   = (const float*)d_in[18];
    const float* W3b   = (const float*)d_in[19];
    float* out = (float*)d_out;

    char* ws = (char*)d_ws;
    size_t off = 0;
    auto alloc = [&](size_t bytes) -> void* {
        void* p = ws + off;
        off = (off + bytes + 255) & ~(size_t)255;
        return p;
    };
    float* trend = (float*)alloc((size_t)BATCH * TN * 4);
    float* S     = (float*)alloc((size_t)BM * 2 * 4);
    int*   idx   = (int*)  alloc((size_t)BM * KNN * 4);
    float* dinv  = (float*)alloc((size_t)BM * 4);
    float* PS    = (float*)alloc((size_t)BM * 2 * 4);
    float* FE    = (float*)alloc((size_t)CFREQ * EMBED * 2 * 4);
    float* Sout  = (float*)alloc((size_t)BM * 2 * 4);
    int*   offs  = (int*)  alloc((size_t)BM * 4);
    int*   rev   = (int*)  alloc((size_t)BM * KNN * 4);
    float* zA    = (float*)alloc((size_t)BM * CFREQ * 2 * 4);
    float* zB    = (float*)alloc((size_t)BM * CFREQ * 2 * 4);
    int*   bsum  = (int*)  alloc((size_t)NBLK * 4);
    int*   bofs  = (int*)  alloc((size_t)NBLK * 4);
    char*  zbase = ws + off;
    int*   cnt   = (int*)  alloc((size_t)BM * 4);
    int*   fptr  = (int*)  alloc((size_t)BM * 4);
    size_t zbytes = (size_t)(ws + off - zbase);

    hipMemsetAsync(zbase, 0, zbytes, stream);   // cnt + fptr only (288 KB)

    trend_kernel<<<(BATCH * TN + 255) / 256, 256, 0, stream>>>(x, trend);
    fft_kernel<<<(BM + 255) / 256, 256, 0, stream>>>(x, trend, S);
    knn_kernel<<<dim3(MNODE / 4, BATCH), 256, 0, stream>>>(S, idx, cnt);
    dinv_kernel<<<(BM + 255) / 256, 256, 0, stream>>>(cnt, S, dinv, PS);
    scan_block_kernel<<<NBLK, 256, 0, stream>>>(cnt, bsum);
    scan_top_kernel<<<1, 256, 0, stream>>>(bsum, bofs);
    scan_apply_kernel<<<NBLK, 256, 0, stream>>>(cnt, bofs, offs);
    fill_kernel<<<(BM * KNN + 255) / 256, 256, 0, stream>>>(idx, offs, fptr, rev);
    gather1_kernel<<<(BM * 4 + 255) / 256, 256, 0, stream>>>(idx, offs, cnt, rev, dinv, PS, zA);
    gather2_kernel<<<(BM * 4 + 255) / 256, 256, 0, stream>>>(idx, offs, cnt, rev, dinv, zA, zB);
    fe_kernel<<<(CFREQ * EMBED + 255) / 256, 256, 0, stream>>>(femb, frWr, frWi, FE);
    rowproj_kernel<<<BM / 4, 256, 0, stream>>>(S, zA, zB, FE, eoWr, eoWi, theta, approx, Sout);
    head_kernel<<<BATCH * NNODE, 128, 0, stream>>>(Sout, trend, n1w, n1b, n2w, n2b,
                                                   W1w, W1b, W2w, W2b, Wtw, Wtb, W3w, W3b, out);
}

// Round 6
// 267.549 us; speedup vs baseline: 1.3072x; 1.2294x over previous
//
#include <hip/hip_runtime.h>
#include <math.h>
#include <float.h>

#define BATCH 16
#define SEQ 96
#define NNODE 256
#define CFREQ 9
#define MNODE (NNODE * CFREQ)      // 2304
#define BM (BATCH * MNODE)         // 36864
#define KNN 8
#define EMBED 128
#define HIDDEN 64
#define TN (SEQ * NNODE)           // 24576
#define KCAP 64
#define NBLK (BM / 256)            // 144 scan blocks
#define HROWS 4                    // head rows per block

__constant__ float COS16[16] = {
    1.0f, 0.9238795325112867f, 0.7071067811865476f, 0.3826834323650898f,
    0.0f, -0.3826834323650898f, -0.7071067811865476f, -0.9238795325112867f,
    -1.0f, -0.9238795325112867f, -0.7071067811865476f, -0.3826834323650898f,
    0.0f, 0.3826834323650898f, 0.7071067811865476f, 0.9238795325112867f};
__constant__ float SIN16[16] = {
    0.0f, 0.3826834323650898f, 0.7071067811865476f, 0.9238795325112867f,
    1.0f, 0.9238795325112867f, 0.7071067811865476f, 0.3826834323650898f,
    0.0f, -0.3826834323650898f, -0.7071067811865476f, -0.9238795325112867f,
    -1.0f, -0.9238795325112867f, -0.7071067811865476f, -0.3826834323650898f};

static __device__ __forceinline__ float silu_f(float x) {
    return x / (1.0f + expf(-x));
}

// ranking value h = |fj|^2 - 2*(fi . fj) (monotone with d = sqi + h)
static __device__ __forceinline__ float rank_h(float2 fj, float xi2, float yi2) {
    float sqj = __fmaf_rn(fj.y, fj.y, __fmul_rn(fj.x, fj.x));
    return __fmaf_rn(xi2, fj.x, __fmaf_rn(yi2, fj.y, sqj));
}

// trend[b,t,n] = (x[t-1]+x[t]+x[t+1])/3 with edge clamp; layout (B,T,N)
__global__ void trend_kernel(const float* __restrict__ x, float* __restrict__ trend) {
    int gid = blockIdx.x * blockDim.x + threadIdx.x;
    if (gid >= BATCH * TN) return;
    int b = gid / TN;
    int rem = gid - b * TN;
    int t = rem / NNODE;
    int n = rem - t * NNODE;
    int tm = t > 0 ? t - 1 : 0;
    int tp = t < SEQ - 1 ? t + 1 : SEQ - 1;
    const float* xb = x + b * TN;
    float v = (xb[tm * NNODE + n] + xb[t * NNODE + n] + xb[tp * NNODE + n]) * (1.0f / 3.0f);
    trend[gid] = v;
}

// S[b, m] = ortho-rfft16 of (x - trend) over first 16 t; m = n*9 + c
__global__ void fft_kernel(const float* __restrict__ x, const float* __restrict__ trend,
                           float* __restrict__ S) {
    int gid = blockIdx.x * blockDim.x + threadIdx.x;
    if (gid >= BM) return;
    int b = gid / MNODE;
    int m = gid - b * MNODE;
    int n = m / CFREQ;
    int c = m - n * CFREQ;
    const float* xb = x + b * TN + n;
    const float* tb = trend + b * TN + n;
    float re = 0.0f, im = 0.0f;
    #pragma unroll
    for (int t = 0; t < 16; ++t) {
        float s = xb[t * NNODE] - tb[t * NNODE];
        int k = (c * t) & 15;
        re += s * COS16[k];
        im -= s * SIN16[k];
    }
    S[gid * 2 + 0] = re * 0.25f;
    S[gid * 2 + 1] = im * 0.25f;
}

// One WAVE per row, 4 rows per 256-block. Exact top-8.
//  P1: h[36] CACHED in registers (VGPR 24 -> ~60, still <= the 64-reg
//      8-waves/EU budget). P2 then needs NO recompute and NO LDS reads,
//      and P1/P2 agreement is exact by construction (same register).
//  T : max over 8 disjoint 8-lane groups of group-min of lane minima
//      (6 shuffles). >=8 candidates have h <= T => T >= true h8.
//  P2: ballot/popcll-prefix append of survivor u64 keys (sortable_h | j)
//      into wave-private LDS buffer; prefix lane-mask hoisted.
//  P3 (guarded: KNN <= total <= KCAP): rank selection via broadcast reads;
//      unique keys -> unique ranks 0..7, initialized slots only.
//  Else: exact fallback from the h cache (insert network + 8-round merge).
__global__ void __launch_bounds__(256, 8) knn_kernel(const float* __restrict__ S,
                                                     int* __restrict__ idx, int* __restrict__ cnt) {
    __shared__ float2 f[MNODE];                        // 18432 B
    __shared__ unsigned long long kbuf[4][KCAP];       // 2048 B -> total 20480 = 160K/8
    int b = blockIdx.y;
    int tid = threadIdx.x;
    for (int t = tid; t < MNODE; t += 256) {
        f[t] = make_float2(S[(b * MNODE + t) * 2 + 0], S[(b * MNODE + t) * 2 + 1]);
    }
    __syncthreads();
    int wave = tid >> 6, lane = tid & 63;
    int i = blockIdx.x * 4 + wave;
    float2 fi = f[i];
    float xi2 = __fmul_rn(-2.0f, fi.x), yi2 = __fmul_rn(-2.0f, fi.y);
    int lane_i = __builtin_amdgcn_readfirstlane(i & 63);
    int k_i    = __builtin_amdgcn_readfirstlane(i >> 6);

    // Phase 1: h cached in regs, per-lane min
    float h[36];
    float mymin = FLT_MAX;
    #pragma unroll
    for (int k = 0; k < 36; ++k) {
        int j = lane + (k << 6);
        float hh = rank_h(f[j], xi2, yi2);
        if (k == k_i && lane == lane_i) hh = FLT_MAX;
        h[k] = hh;
        mymin = fminf(mymin, hh);
    }
    // Threshold: 6 dependent shuffles. Group-min (lanes differing in bits 0-2),
    // then max across the 8 groups (bits 3-5).
    float g = mymin;
    g = fminf(g, __shfl_xor(g, 1, 64));
    g = fminf(g, __shfl_xor(g, 2, 64));
    g = fminf(g, __shfl_xor(g, 4, 64));
    float T = g;
    T = fmaxf(T, __shfl_xor(T, 8, 64));
    T = fmaxf(T, __shfl_xor(T, 16, 64));
    T = fmaxf(T, __shfl_xor(T, 32, 64));
    // Phase 2: ballot-compacted append of survivors' keys (from the cache)
    unsigned long long* mybuf = kbuf[wave];
    const unsigned long long lmask = (1ull << lane) - 1ull;
    int total = 0;
    #pragma unroll
    for (int k = 0; k < 36; ++k) {
        bool pred = h[k] <= T;
        unsigned long long mask = __ballot(pred);
        if (pred) {
            int pos = total + (int)__popcll(mask & lmask);
            if (pos < KCAP) {
                unsigned int bits = __float_as_uint(h[k]);
                if (bits == 0x80000000u) bits = 0u;
                unsigned int s = bits ^ (unsigned int)(((int)bits >> 31) | 0x80000000);
                mybuf[pos] = ((unsigned long long)s << 32) | (unsigned int)(lane + (k << 6));
            }
        }
        total += (int)__popcll(mask);
    }
    // no block barrier: kbuf[wave] is wave-private; same-wave DS ops in-order

    if (total >= KNN && total <= KCAP) {
        // Phase 3: rank selection over the survivor list (broadcast reads)
        for (int p = lane; p < total; p += 64) {
            unsigned long long mykey = mybuf[p];
            int rank = 0;
            for (int q = 0; q < total; ++q) {
                rank += (mybuf[q] < mykey) ? 1 : 0;
            }
            if (rank < KNN) {
                int j = (int)(unsigned int)(mykey & 0xFFFFFFFFull);
                idx[(b * MNODE + i) * KNN + rank] = j;
                atomicAdd(&cnt[b * MNODE + j], 1);
            }
        }
    } else {
        // exact fallback from the h cache: per-lane insert network +
        // 8-round extract-min merge (always writes exactly 8 valid entries)
        const unsigned long long SENT = ~0ull;
        unsigned long long k0 = SENT, k1 = SENT, k2 = SENT, k3 = SENT,
                           k4 = SENT, k5 = SENT, k6 = SENT, k7 = SENT;
        #pragma unroll
        for (int k = 0; k < 36; ++k) {
            unsigned int bits = __float_as_uint(h[k]);
            if (bits == 0x80000000u) bits = 0u;
            unsigned int s = bits ^ (unsigned int)(((int)bits >> 31) | 0x80000000);
            unsigned long long key = ((unsigned long long)s << 32) | (unsigned int)(lane + (k << 6));
            if (key < k7) {
                k7 = key;
                if (k7 < k6) { unsigned long long t = k6; k6 = k7; k7 = t; }
                if (k6 < k5) { unsigned long long t = k5; k5 = k6; k6 = t; }
                if (k5 < k4) { unsigned long long t = k4; k4 = k5; k5 = t; }
                if (k4 < k3) { unsigned long long t = k3; k3 = k4; k4 = t; }
                if (k3 < k2) { unsigned long long t = k2; k2 = k3; k3 = t; }
                if (k2 < k1) { unsigned long long t = k1; k1 = k2; k2 = t; }
                if (k1 < k0) { unsigned long long t = k0; k0 = k1; k1 = t; }
            }
        }
        unsigned long long mywin = 0;
        #pragma unroll
        for (int r = 0; r < KNN; ++r) {
            unsigned long long hh = k0;
            #pragma unroll
            for (int off = 32; off > 0; off >>= 1) {
                unsigned long long o = __shfl_xor(hh, off, 64);
                if (o < hh) hh = o;
            }
            if (lane == r) mywin = hh;
            if (k0 == hh) {
                k0 = k1; k1 = k2; k2 = k3; k3 = k4; k4 = k5; k5 = k6; k6 = k7; k7 = SENT;
            }
        }
        if (lane < KNN) {
            int j = (int)(unsigned int)(mywin & 0xFFFFFFFFull);
            idx[(b * MNODE + i) * KNN + lane] = j;
            atomicAdd(&cnt[b * MNODE + j], 1);
        }
    }
}

// dinv[j] = 1/sqrt(deg+eps); PS[j] = dinv[j] * S[j]  (pre-folded for gather1)
__global__ void dinv_kernel(const int* __restrict__ cnt, const float* __restrict__ S,
                            float* __restrict__ dinv, float* __restrict__ PS) {
    int gid = blockIdx.x * blockDim.x + threadIdx.x;
    if (gid >= BM) return;
    float deg = (float)(KNN + cnt[gid]);
    float dv = 1.0f / sqrtf(deg + 1e-8f);
    dinv[gid] = dv;
    PS[gid * 2 + 0] = dv * S[gid * 2 + 0];
    PS[gid * 2 + 1] = dv * S[gid * 2 + 1];
}

// --- coalesced 3-stage exclusive scan over cnt[BM] -> offs[BM] ---
__global__ void __launch_bounds__(256) scan_block_kernel(const int* __restrict__ cnt,
                                                         int* __restrict__ bsum) {
    __shared__ int wsum[4];
    int tid = threadIdx.x;
    int v = cnt[blockIdx.x * 256 + tid];
    int s = v;
    #pragma unroll
    for (int off = 32; off > 0; off >>= 1) s += __shfl_down(s, off, 64);
    if ((tid & 63) == 0) wsum[tid >> 6] = s;
    __syncthreads();
    if (tid == 0) bsum[blockIdx.x] = wsum[0] + wsum[1] + wsum[2] + wsum[3];
}
__global__ void __launch_bounds__(256) scan_top_kernel(const int* __restrict__ bsum,
                                                       int* __restrict__ bofs) {
    __shared__ int buf[NBLK];
    int tid = threadIdx.x;
    if (tid < NBLK) buf[tid] = bsum[tid];
    __syncthreads();
    if (tid == 0) {
        int run = 0;
        for (int t = 0; t < NBLK; ++t) { int v = buf[t]; buf[t] = run; run += v; }
    }
    __syncthreads();
    if (tid < NBLK) bofs[tid] = buf[tid];
}
__global__ void __launch_bounds__(256) scan_apply_kernel(const int* __restrict__ cnt,
                                                         const int* __restrict__ bofs,
                                                         int* __restrict__ offs) {
    __shared__ int wsum[4];
    int tid = threadIdx.x;
    int gid = blockIdx.x * 256 + tid;
    int lane = tid & 63, wv = tid >> 6;
    int v = cnt[gid];
    int x = v;
    #pragma unroll
    for (int off = 1; off < 64; off <<= 1) {
        int y = __shfl_up(x, off, 64);
        if (lane >= off) x += y;
    }
    if (lane == 63) wsum[wv] = x;
    __syncthreads();
    int base = bofs[blockIdx.x];
    for (int w = 0; w < wv; ++w) base += wsum[w];
    offs[gid] = base + x - v;
}

// scatter each directed edge i->j into j's reverse list (int atomics for slots)
__global__ void fill_kernel(const int* __restrict__ idx, const int* __restrict__ offs,
                            int* __restrict__ fptr, int* __restrict__ rev) {
    int gid = blockIdx.x * blockDim.x + threadIdx.x;
    if (gid >= BM * KNN) return;
    int b = gid / (MNODE * KNN);
    int rem = gid - b * (MNODE * KNN);
    int i = rem / KNN;
    int gj = b * MNODE + idx[gid];
    int pos = atomicAdd(&fptr[gj], 1);
    rev[offs[gj] + pos] = b * MNODE + i;
}

// zA[i][c] = 0.5*dinv[i] * sum over neighbors j (both directions) with j%9==c of PS[j]
// 4 threads per row (c-quarters {0-2},{3-4},{5-6},{7-8}); static 6-float acc.
__global__ void __launch_bounds__(256) gather1_kernel(
    const int* __restrict__ idx, const int* __restrict__ offs, const int* __restrict__ cnt,
    const int* __restrict__ rev, const float* __restrict__ dinv, const float* __restrict__ PS,
    float* __restrict__ zA) {
    int gid = blockIdx.x * blockDim.x + threadIdx.x;
    if (gid >= BM * 4) return;
    int gi = gid >> 2;
    int q = gid & 3;
    int c0 = (q == 0) ? 0 : (1 + 2 * q);          // 0,3,5,7
    int nc = (q == 0) ? 3 : 2;
    int b = gi / MNODE;
    float a0 = 0.0f, a1 = 0.0f, a2 = 0.0f, a3 = 0.0f, a4 = 0.0f, a5 = 0.0f;
    #pragma unroll
    for (int k = 0; k < KNN; ++k) {
        int gj = b * MNODE + idx[gi * KNN + k];
        int rel = gj % CFREQ - c0;
        float2 p = ((const float2*)PS)[gj];
        bool t0 = (rel == 0), t1 = (rel == 1), t2 = (rel == 2) && (nc == 3);
        a0 += t0 ? p.x : 0.0f;  a1 += t0 ? p.y : 0.0f;
        a2 += t1 ? p.x : 0.0f;  a3 += t1 ? p.y : 0.0f;
        a4 += t2 ? p.x : 0.0f;  a5 += t2 ? p.y : 0.0f;
    }
    int o = offs[gi], e = o + cnt[gi];
    for (int p_ = o; p_ < e; ++p_) {
        int gk = rev[p_];
        int rel = gk % CFREQ - c0;
        float2 p = ((const float2*)PS)[gk];
        bool t0 = (rel == 0), t1 = (rel == 1), t2 = (rel == 2) && (nc == 3);
        a0 += t0 ? p.x : 0.0f;  a1 += t0 ? p.y : 0.0f;
        a2 += t1 ? p.x : 0.0f;  a3 += t1 ? p.y : 0.0f;
        a4 += t2 ? p.x : 0.0f;  a5 += t2 ? p.y : 0.0f;
    }
    float s = dinv[gi] * 0.5f;
    zA[(gi * CFREQ + c0 + 0) * 2 + 0] = s * a0;
    zA[(gi * CFREQ + c0 + 0) * 2 + 1] = s * a1;
    zA[(gi * CFREQ + c0 + 1) * 2 + 0] = s * a2;
    zA[(gi * CFREQ + c0 + 1) * 2 + 1] = s * a3;
    if (nc == 3) {
        zA[(gi * CFREQ + c0 + 2) * 2 + 0] = s * a4;
        zA[(gi * CFREQ + c0 + 2) * 2 + 1] = s * a5;
    }
}

// zB[i][c] = sum over neighbors j (both directions) of w_ij * zA[j][c]
// 4 threads per row (c-quarters) for occupancy.
__global__ void __launch_bounds__(256) gather2_kernel(
    const int* __restrict__ idx, const int* __restrict__ offs, const int* __restrict__ cnt,
    const int* __restrict__ rev, const float* __restrict__ dinv, const float* __restrict__ zA,
    float* __restrict__ zB) {
    int gid = blockIdx.x * blockDim.x + threadIdx.x;
    if (gid >= BM * 4) return;
    int gi = gid >> 2;
    int q = gid & 3;
    int c0 = (q == 0) ? 0 : (1 + 2 * q);          // 0,3,5,7
    int nc = (q == 0) ? 3 : 2;
    int b = gi / MNODE;
    float acc[6];
    #pragma unroll
    for (int k = 0; k < 6; ++k) acc[k] = 0.0f;
    float di = dinv[gi] * 0.5f;
    #pragma unroll
    for (int k = 0; k < KNN; ++k) {
        int gj = b * MNODE + idx[gi * KNN + k];
        float w = di * dinv[gj];
        const float2* za = (const float2*)(zA + gj * 2 * CFREQ) + c0;
        #pragma unroll
        for (int c = 0; c < 3; ++c) {
            if (c < nc) {
                float2 v = za[c];
                acc[2 * c + 0] += w * v.x;
                acc[2 * c + 1] += w * v.y;
            }
        }
    }
    int o = offs[gi], e = o + cnt[gi];
    for (int p = o; p < e; ++p) {
        int gk = rev[p];
        float w = di * dinv[gk];
        const float2* za = (const float2*)(zA + gk * 2 * CFREQ) + c0;
        #pragma unroll
        for (int c = 0; c < 3; ++c) {
            if (c < nc) {
                float2 v = za[c];
                acc[2 * c + 0] += w * v.x;
                acc[2 * c + 1] += w * v.y;
            }
        }
    }
    #pragma unroll
    for (int c = 0; c < 3; ++c) {
        if (c < nc) {
            zB[(gi * CFREQ + c0 + c) * 2 + 0] = acc[2 * c + 0];
            zB[(gi * CFREQ + c0 + c) * 2 + 1] = acc[2 * c + 1];
        }
    }
}

// FE[c,e] = freq_emb[c,:] @ (Wr + i Wi)^T  (9 x 128 complex)
__global__ void fe_kernel(const float* __restrict__ femb, const float* __restrict__ Wr,
                          const float* __restrict__ Wi, float* __restrict__ FE) {
    int gid = blockIdx.x * blockDim.x + threadIdx.x;
    if (gid >= CFREQ * EMBED) return;
    int c = gid / EMBED;
    int e = gid - c * EMBED;
    float ar = 0.0f, ai = 0.0f;
    for (int k = 0; k < EMBED; ++k) {
        float f = femb[c * EMBED + k];
        ar += f * Wr[e * EMBED + k];
        ai += f * Wi[e * EMBED + k];
    }
    FE[gid * 2 + 0] = ar;
    FE[gid * 2 + 1] = ai;
}

// per row r: z_acc (9 complex) -> u = z_acc . FE -> csilu -> eo projection (complex scalar)
__global__ void __launch_bounds__(256) rowproj_kernel(
    const float* __restrict__ S, const float* __restrict__ zA, const float* __restrict__ zB,
    const float* __restrict__ FE, const float* __restrict__ eoWr, const float* __restrict__ eoWi,
    const float* __restrict__ theta, const float* __restrict__ approx,
    float* __restrict__ Sout) {
    int wave = threadIdx.x >> 6;
    int lane = threadIdx.x & 63;
    int r = blockIdx.x * 4 + wave;
    if (r >= BM) return;
    float a0 = theta[0] * approx[0] + theta[1] * approx[3];
    float a1 = theta[0] * approx[1] + theta[1] * approx[4];
    float a2 = theta[0] * approx[2] + theta[1] * approx[5];
    float ca = a0 - a2, cb = -a1, cc = 2.0f * a2;
    int cr = r % CFREQ;
    float sr = S[r * 2 + 0], si = S[r * 2 + 1];
    int e1 = lane + 64;
    float ur0 = 0.0f, ui0 = 0.0f, ur1 = 0.0f, ui1 = 0.0f;
    #pragma unroll
    for (int c = 0; c < CFREQ; ++c) {
        float zr = cb * zA[(r * CFREQ + c) * 2 + 0] + cc * zB[(r * CFREQ + c) * 2 + 0];
        float zi = cb * zA[(r * CFREQ + c) * 2 + 1] + cc * zB[(r * CFREQ + c) * 2 + 1];
        if (c == cr) { zr += ca * sr; zi += ca * si; }
        float fr0 = FE[(c * EMBED + lane) * 2 + 0], fi0 = FE[(c * EMBED + lane) * 2 + 1];
        float fr1 = FE[(c * EMBED + e1) * 2 + 0],  fi1 = FE[(c * EMBED + e1) * 2 + 1];
        ur0 += zr * fr0 - zi * fi0;  ui0 += zr * fi0 + zi * fr0;
        ur1 += zr * fr1 - zi * fi1;  ui1 += zr * fi1 + zi * fr1;
    }
    float hr0 = silu_f(ur0), hi0 = silu_f(ui0);
    float hr1 = silu_f(ur1), hi1 = silu_f(ui1);
    float wr0 = eoWr[lane], wi0 = eoWi[lane], wr1 = eoWr[e1], wi1 = eoWi[e1];
    float p = hr0 * wr0 - hi0 * wi0 + hr1 * wr1 - hi1 * wi1;
    float q = hr0 * wi0 + hi0 * wr0 + hr1 * wi1 + hi1 * wr1;
    #pragma unroll
    for (int off = 32; off > 0; off >>= 1) {
        p += __shfl_down(p, off, 64);
        q += __shfl_down(q, off, 64);
    }
    if (lane == 0) {
        Sout[r * 2 + 0] = p;
        Sout[r * 2 + 1] = q;
    }
}

// per (b,n): irfft96 -> inorm+silu -> W1 -> inorm+silu -> W2 -> + trend_emb -> W3 -> out
// HROWS=4 rows per 256-thread block: weight staging amortized 4x, matvec
// phases use wave g's 64 lanes = row g's 64 outputs (100% utilization),
// inorm2 is pure in-wave shuffles.
__global__ void __launch_bounds__(256) head_kernel(
    const float* __restrict__ Sout, const float* __restrict__ trend,
    const float* __restrict__ n1w, const float* __restrict__ n1b,
    const float* __restrict__ n2w, const float* __restrict__ n2b,
    const float* __restrict__ W1w, const float* __restrict__ W1b,
    const float* __restrict__ W2w, const float* __restrict__ W2b,
    const float* __restrict__ Wtw, const float* __restrict__ Wtb,
    const float* __restrict__ W3w, const float* __restrict__ W3b,
    float* __restrict__ out) {
    __shared__ float tabc[96], tabs[96];
    __shared__ float srow[HROWS][18];
    __shared__ float tbuf[HROWS][96];
    __shared__ float hraw[HROWS][96];
    __shared__ float sH[HROWS][96];
    __shared__ float h2[HROWS][64];
    __shared__ float s3[HROWS][64];
    __shared__ float red[HROWS][2];
    __shared__ float wbuf[6240];
    int tid = threadIdx.x;
    int wave = tid >> 6, lane = tid & 63;
    int bn0 = blockIdx.x * HROWS;
    if (tid < 96) {
        double a = 6.283185307179586476925286766559 * (double)tid / 96.0;
        tabc[tid] = (float)cos(a);
        tabs[tid] = (float)sin(a);
    }
    for (int i = tid; i < HROWS * 96; i += 256) {
        int g = i / 96, t = i - g * 96;
        int bn = bn0 + g;
        tbuf[g][t] = trend[(bn >> 8) * TN + t * NNODE + (bn & 255)];
    }
    if (tid < HROWS * 18) {
        int g = tid / 18, k = tid - g * 18;
        srow[g][k] = Sout[(bn0 + g) * 18 + k];
    }
    __syncthreads();
    // irfft96 for all 4 rows
    for (int i = tid; i < HROWS * 96; i += 256) {
        int g = i / 96, t = i - g * 96;
        float acc = srow[g][0];   // Im(bin0) ignored by irfft
        #pragma unroll
        for (int c = 1; c < CFREQ; ++c) {
            int k = (c * t) % 96;
            acc += 2.0f * (srow[g][2 * c] * tabc[k] - srow[g][2 * c + 1] * tabs[k]);
        }
        hraw[g][t] = acc * 0.10206207261596575f;  // 1/sqrt(96)
    }
    __syncthreads();
    // mean of row `wave`
    {
        float v = hraw[wave][lane] + ((lane < 32) ? hraw[wave][64 + lane] : 0.0f);
        #pragma unroll
        for (int off = 32; off > 0; off >>= 1) v += __shfl_down(v, off, 64);
        if (lane == 0) red[wave][0] = v * (1.0f / 96.0f);
    }
    __syncthreads();
    // var of row `wave`
    {
        float mu = red[wave][0];
        float d0 = hraw[wave][lane] - mu;
        float v = d0 * d0;
        if (lane < 32) { float d1 = hraw[wave][64 + lane] - mu; v += d1 * d1; }
        #pragma unroll
        for (int off = 32; off > 0; off >>= 1) v += __shfl_down(v, off, 64);
        if (lane == 0) red[wave][1] = v * (1.0f / 96.0f);
    }
    __syncthreads();
    // inorm1 + silu -> sH; stage W1 (97-pad)
    for (int i = tid; i < HROWS * 96; i += 256) {
        int g = i / 96, t = i - g * 96;
        int n = (bn0 + g) & 255;
        float xn = (hraw[g][t] - red[g][0]) / sqrtf(red[g][1] + 1e-5f) * n1w[n] + n1b[n];
        sH[g][t] = silu_f(xn);
    }
    for (int i = tid; i < HIDDEN * 96; i += 256) {
        int rr = i / 96;
        wbuf[rr * 97 + (i - rr * 96)] = W1w[i];
    }
    __syncthreads();
    // W1 matvec: wave g, lane r
    float v1;
    {
        float acc = W1b[lane];
        #pragma unroll 8
        for (int t = 0; t < 96; ++t) acc += sH[wave][t] * wbuf[lane * 97 + t];
        v1 = acc;
    }
    // inorm2 + silu (pure in-wave) -> h2
    {
        float s = v1;
        #pragma unroll
        for (int off = 32; off > 0; off >>= 1) s += __shfl_down(s, off, 64);
        s = __shfl(s, 0, 64);
        float mu2 = s * (1.0f / 64.0f);
        float d = v1 - mu2;
        float vs = d * d;
        #pragma unroll
        for (int off = 32; off > 0; off >>= 1) vs += __shfl_down(vs, off, 64);
        vs = __shfl(vs, 0, 64);
        float var2 = vs * (1.0f / 64.0f);
        int n = (bn0 + wave) & 255;
        float xn = (v1 - mu2) / sqrtf(var2 + 1e-5f) * n2w[n] + n2b[n];
        h2[wave][lane] = silu_f(xn);
    }
    __syncthreads();   // wbuf(W1) reads + h2 writes done
    for (int i = tid; i < HIDDEN * HIDDEN; i += 256) {
        wbuf[(i >> 6) * 65 + (i & 63)] = W2w[i];
    }
    __syncthreads();
    float v3;
    {
        float acc = W2b[lane];
        #pragma unroll 8
        for (int h = 0; h < 64; ++h) acc += h2[wave][h] * wbuf[lane * 65 + h];
        v3 = acc;
    }
    __syncthreads();   // wbuf(W2) reads done
    for (int i = tid; i < HIDDEN * 96; i += 256) {
        int rr = i / 96;
        wbuf[rr * 97 + (i - rr * 96)] = Wtw[i];
    }
    __syncthreads();
    {
        float acc = Wtb[lane];
        #pragma unroll 8
        for (int t = 0; t < 96; ++t) acc += tbuf[wave][t] * wbuf[lane * 97 + t];
        s3[wave][lane] = v3 + acc;
    }
    __syncthreads();   // wbuf(Wt) reads + s3 writes done
    for (int i = tid; i < 96 * HIDDEN; i += 256) {
        wbuf[(i >> 6) * 65 + (i & 63)] = W3w[i];
    }
    __syncthreads();
    for (int i = tid; i < HROWS * 96; i += 256) {
        int g = i / 96, t = i - g * 96;
        float acc = W3b[t];
        #pragma unroll 8
        for (int h = 0; h < 64; ++h) acc += s3[g][h] * wbuf[t * 65 + h];
        out[(bn0 + g) * 96 + t] = acc;
    }
}

extern "C" void kernel_launch(void* const* d_in, const int* in_sizes, int n_in,
                              void* d_out, int out_size, void* d_ws, size_t ws_size,
                              hipStream_t stream) {
    const float* x     = (const float*)d_in[0];
    const float* approx= (const float*)d_in[1];
    const float* theta = (const float*)d_in[2];
    const float* frWr  = (const float*)d_in[3];
    const float* frWi  = (const float*)d_in[4];
    const float* eoWr  = (const float*)d_in[5];
    const float* eoWi  = (const float*)d_in[6];
    const float* femb  = (const float*)d_in[7];
    const float* n1w   = (const float*)d_in[8];
    const float* n1b   = (const float*)d_in[9];
    const float* n2w   = (const float*)d_in[10];
    const float* n2b   = (const float*)d_in[11];
    const float* W1w   = (const float*)d_in[12];
    const float* W1b   = (const float*)d_in[13];
    const float* W2w   = (const float*)d_in[14];
    const float* W2b   = (const float*)d_in[15];
    const float* Wtw   = (const float*)d_in[16];
    const float* Wtb   = (const float*)d_in[17];
    const float* W3w   = (const float*)d_in[18];
    const float* W3b   = (const float*)d_in[19];
    float* out = (float*)d_out;

    char* ws = (char*)d_ws;
    size_t off = 0;
    auto alloc = [&](size_t bytes) -> void* {
        void* p = ws + off;
        off = (off + bytes + 255) & ~(size_t)255;
        return p;
    };
    float* trend = (float*)alloc((size_t)BATCH * TN * 4);
    float* S     = (float*)alloc((size_t)BM * 2 * 4);
    int*   idx   = (int*)  alloc((size_t)BM * KNN * 4);
    float* dinv  = (float*)alloc((size_t)BM * 4);
    float* PS    = (float*)alloc((size_t)BM * 2 * 4);
    float* FE    = (float*)alloc((size_t)CFREQ * EMBED * 2 * 4);
    float* Sout  = (float*)alloc((size_t)BM * 2 * 4);
    int*   offs  = (int*)  alloc((size_t)BM * 4);
    int*   rev   = (int*)  alloc((size_t)BM * KNN * 4);
    float* zA    = (float*)alloc((size_t)BM * CFREQ * 2 * 4);
    float* zB    = (float*)alloc((size_t)BM * CFREQ * 2 * 4);
    int*   bsum  = (int*)  alloc((size_t)NBLK * 4);
    int*   bofs  = (int*)  alloc((size_t)NBLK * 4);
    char*  zbase = ws + off;
    int*   cnt   = (int*)  alloc((size_t)BM * 4);
    int*   fptr  = (int*)  alloc((size_t)BM * 4);
    size_t zbytes = (size_t)(ws + off - zbase);

    hipMemsetAsync(zbase, 0, zbytes, stream);   // cnt + fptr only (288 KB)

    trend_kernel<<<(BATCH * TN + 255) / 256, 256, 0, stream>>>(x, trend);
    fft_kernel<<<(BM + 255) / 256, 256, 0, stream>>>(x, trend, S);
    knn_kernel<<<dim3(MNODE / 4, BATCH), 256, 0, stream>>>(S, idx, cnt);
    dinv_kernel<<<(BM + 255) / 256, 256, 0, stream>>>(cnt, S, dinv, PS);
    scan_block_kernel<<<NBLK, 256, 0, stream>>>(cnt, bsum);
    scan_top_kernel<<<1, 256, 0, stream>>>(bsum, bofs);
    scan_apply_kernel<<<NBLK, 256, 0, stream>>>(cnt, bofs, offs);
    fill_kernel<<<(BM * KNN + 255) / 256, 256, 0, stream>>>(idx, offs, fptr, rev);
    gather1_kernel<<<(BM * 4 + 255) / 256, 256, 0, stream>>>(idx, offs, cnt, rev, dinv, PS, zA);
    gather2_kernel<<<(BM * 4 + 255) / 256, 256, 0, stream>>>(idx, offs, cnt, rev, dinv, zA, zB);
    fe_kernel<<<(CFREQ * EMBED + 255) / 256, 256, 0, stream>>>(femb, frWr, frWi, FE);
    rowproj_kernel<<<BM / 4, 256, 0, stream>>>(S, zA, zB, FE, eoWr, eoWi, theta, approx, Sout);
    head_kernel<<<BATCH * NNODE / HROWS, 256, 0, stream>>>(Sout, trend, n1w, n1b, n2w, n2b,
                                                           W1w, W1b, W2w, W2b, Wtw, Wtb, W3w, W3b, out);
}

// Round 7
// 260.286 us; speedup vs baseline: 1.3437x; 1.0279x over previous
//
#include <hip/hip_runtime.h>
#include <math.h>
#include <float.h>

#define BATCH 16
#define SEQ 96
#define NNODE 256
#define CFREQ 9
#define MNODE (NNODE * CFREQ)      // 2304
#define BM (BATCH * MNODE)         // 36864
#define KNN 8
#define EMBED 128
#define HIDDEN 64
#define TN (SEQ * NNODE)           // 24576
#define KCAP 64
#define NBLK (BM / 256)            // 144 scan blocks
#define HROWS 4                    // head rows per block

__constant__ float COS16[16] = {
    1.0f, 0.9238795325112867f, 0.7071067811865476f, 0.3826834323650898f,
    0.0f, -0.3826834323650898f, -0.7071067811865476f, -0.9238795325112867f,
    -1.0f, -0.9238795325112867f, -0.7071067811865476f, -0.3826834323650898f,
    0.0f, 0.3826834323650898f, 0.7071067811865476f, 0.9238795325112867f};
__constant__ float SIN16[16] = {
    0.0f, 0.3826834323650898f, 0.7071067811865476f, 0.9238795325112867f,
    1.0f, 0.9238795325112867f, 0.7071067811865476f, 0.3826834323650898f,
    0.0f, -0.3826834323650898f, -0.7071067811865476f, -0.9238795325112867f,
    -1.0f, -0.9238795325112867f, -0.7071067811865476f, -0.3826834323650898f};

static __device__ __forceinline__ float silu_f(float x) {
    return x / (1.0f + expf(-x));
}

// ranking value h = |fj|^2 - 2*(fi . fj) (monotone with d = sqi + h)
static __device__ __forceinline__ float rank_h(float2 fj, float xi2, float yi2) {
    float sqj = __fmaf_rn(fj.y, fj.y, __fmul_rn(fj.x, fj.x));
    return __fmaf_rn(xi2, fj.x, __fmaf_rn(yi2, fj.y, sqj));
}

// trend[b,t,n] = (x[t-1]+x[t]+x[t+1])/3 with edge clamp; layout (B,T,N)
__global__ void trend_kernel(const float* __restrict__ x, float* __restrict__ trend) {
    int gid = blockIdx.x * blockDim.x + threadIdx.x;
    if (gid >= BATCH * TN) return;
    int b = gid / TN;
    int rem = gid - b * TN;
    int t = rem / NNODE;
    int n = rem - t * NNODE;
    int tm = t > 0 ? t - 1 : 0;
    int tp = t < SEQ - 1 ? t + 1 : SEQ - 1;
    const float* xb = x + b * TN;
    float v = (xb[tm * NNODE + n] + xb[t * NNODE + n] + xb[tp * NNODE + n]) * (1.0f / 3.0f);
    trend[gid] = v;
}

// S[b, m] = ortho-rfft16 of (x - trend) over first 16 t; m = n*9 + c
__global__ void fft_kernel(const float* __restrict__ x, const float* __restrict__ trend,
                           float* __restrict__ S) {
    int gid = blockIdx.x * blockDim.x + threadIdx.x;
    if (gid >= BM) return;
    int b = gid / MNODE;
    int m = gid - b * MNODE;
    int n = m / CFREQ;
    int c = m - n * CFREQ;
    const float* xb = x + b * TN + n;
    const float* tb = trend + b * TN + n;
    float re = 0.0f, im = 0.0f;
    #pragma unroll
    for (int t = 0; t < 16; ++t) {
        float s = xb[t * NNODE] - tb[t * NNODE];
        int k = (c * t) & 15;
        re += s * COS16[k];
        im -= s * SIN16[k];
    }
    S[gid * 2 + 0] = re * 0.25f;
    S[gid * 2 + 1] = im * 0.25f;
}

// One WAVE per row, 4 rows per 256-block. Exact top-8.
//  P1: h[36] cached in regs; per-lane min.
//  T : max over 8 disjoint 8-lane groups of group-min of lane minima
//      (6 shuffles). >=8 candidates have h <= T => T >= true h8.
//  P2: ballot/popcll-prefix append of survivor u64 keys (sortable_h | j)
//      into wave-private LDS buffer.
//  P3 (guarded: KNN <= total <= KCAP): pad survivor list to multiple of 8
//      with SENT (real keys always < SENT -> rank unaffected), then rank
//      selection with 8 keys per iteration via 4x ds_read_b128 (independent
//      loads pipeline; kills the serial per-key LDS-read chain).
//  Else: exact fallback from the h cache (insert network + 8-round merge).
__global__ void __launch_bounds__(256, 8) knn_kernel(const float* __restrict__ S,
                                                     int* __restrict__ idx, int* __restrict__ cnt) {
    __shared__ float2 f[MNODE];                        // 18432 B
    __shared__ unsigned long long kbuf[4][KCAP];       // 2048 B -> total 20480 = 160K/8
    int b = blockIdx.y;
    int tid = threadIdx.x;
    for (int t = tid; t < MNODE; t += 256) {
        f[t] = make_float2(S[(b * MNODE + t) * 2 + 0], S[(b * MNODE + t) * 2 + 1]);
    }
    __syncthreads();
    int wave = tid >> 6, lane = tid & 63;
    int i = blockIdx.x * 4 + wave;
    float2 fi = f[i];
    float xi2 = __fmul_rn(-2.0f, fi.x), yi2 = __fmul_rn(-2.0f, fi.y);
    int lane_i = __builtin_amdgcn_readfirstlane(i & 63);
    int k_i    = __builtin_amdgcn_readfirstlane(i >> 6);

    // Phase 1: h cached in regs, per-lane min
    float h[36];
    float mymin = FLT_MAX;
    #pragma unroll
    for (int k = 0; k < 36; ++k) {
        int j = lane + (k << 6);
        float hh = rank_h(f[j], xi2, yi2);
        if (k == k_i && lane == lane_i) hh = FLT_MAX;
        h[k] = hh;
        mymin = fminf(mymin, hh);
    }
    // Threshold: 6 dependent shuffles. Group-min (lanes differing in bits 0-2),
    // then max across the 8 groups (bits 3-5).
    float g = mymin;
    g = fminf(g, __shfl_xor(g, 1, 64));
    g = fminf(g, __shfl_xor(g, 2, 64));
    g = fminf(g, __shfl_xor(g, 4, 64));
    float T = g;
    T = fmaxf(T, __shfl_xor(T, 8, 64));
    T = fmaxf(T, __shfl_xor(T, 16, 64));
    T = fmaxf(T, __shfl_xor(T, 32, 64));
    // Phase 2: ballot-compacted append of survivors' keys (from the cache)
    unsigned long long* mybuf = kbuf[wave];
    const unsigned long long lmask = (1ull << lane) - 1ull;
    int total = 0;
    #pragma unroll
    for (int k = 0; k < 36; ++k) {
        bool pred = h[k] <= T;
        unsigned long long mask = __ballot(pred);
        if (pred) {
            int pos = total + (int)__popcll(mask & lmask);
            if (pos < KCAP) {
                unsigned int bits = __float_as_uint(h[k]);
                if (bits == 0x80000000u) bits = 0u;
                unsigned int s = bits ^ (unsigned int)(((int)bits >> 31) | 0x80000000);
                mybuf[pos] = ((unsigned long long)s << 32) | (unsigned int)(lane + (k << 6));
            }
        }
        total += (int)__popcll(mask);
    }
    // no block barrier: kbuf[wave] is wave-private; same-wave DS ops in-order

    if (total >= KNN && total <= KCAP) {
        // Phase 3: pad to multiple of 8 with SENT, then 8-wide rank selection
        int padded = (total + 7) & ~7;                 // <= KCAP (64) always
        if (lane < padded - total) mybuf[total + lane] = ~0ull;
        for (int p = lane; p < total; p += 64) {
            unsigned long long mykey = mybuf[p];
            int rank = 0;
            for (int q = 0; q < padded; q += 8) {
                const ulonglong2* bp = (const ulonglong2*)&mybuf[q];
                ulonglong2 a = bp[0], b2 = bp[1], c2 = bp[2], d2 = bp[3];
                rank += (int)(a.x  < mykey) + (int)(a.y  < mykey)
                      + (int)(b2.x < mykey) + (int)(b2.y < mykey)
                      + (int)(c2.x < mykey) + (int)(c2.y < mykey)
                      + (int)(d2.x < mykey) + (int)(d2.y < mykey);
            }
            if (rank < KNN) {
                int j = (int)(unsigned int)(mykey & 0xFFFFFFFFull);
                idx[(b * MNODE + i) * KNN + rank] = j;
                atomicAdd(&cnt[b * MNODE + j], 1);
            }
        }
    } else {
        // exact fallback from the h cache: per-lane insert network +
        // 8-round extract-min merge (always writes exactly 8 valid entries)
        const unsigned long long SENT = ~0ull;
        unsigned long long k0 = SENT, k1 = SENT, k2 = SENT, k3 = SENT,
                           k4 = SENT, k5 = SENT, k6 = SENT, k7 = SENT;
        #pragma unroll
        for (int k = 0; k < 36; ++k) {
            unsigned int bits = __float_as_uint(h[k]);
            if (bits == 0x80000000u) bits = 0u;
            unsigned int s = bits ^ (unsigned int)(((int)bits >> 31) | 0x80000000);
            unsigned long long key = ((unsigned long long)s << 32) | (unsigned int)(lane + (k << 6));
            if (key < k7) {
                k7 = key;
                if (k7 < k6) { unsigned long long t = k6; k6 = k7; k7 = t; }
                if (k6 < k5) { unsigned long long t = k5; k5 = k6; k6 = t; }
                if (k5 < k4) { unsigned long long t = k4; k4 = k5; k5 = t; }
                if (k4 < k3) { unsigned long long t = k3; k3 = k4; k4 = t; }
                if (k3 < k2) { unsigned long long t = k2; k2 = k3; k3 = t; }
                if (k2 < k1) { unsigned long long t = k1; k1 = k2; k2 = t; }
                if (k1 < k0) { unsigned long long t = k0; k0 = k1; k1 = t; }
            }
        }
        unsigned long long mywin = 0;
        #pragma unroll
        for (int r = 0; r < KNN; ++r) {
            unsigned long long hh = k0;
            #pragma unroll
            for (int off = 32; off > 0; off >>= 1) {
                unsigned long long o = __shfl_xor(hh, off, 64);
                if (o < hh) hh = o;
            }
            if (lane == r) mywin = hh;
            if (k0 == hh) {
                k0 = k1; k1 = k2; k2 = k3; k3 = k4; k4 = k5; k5 = k6; k6 = k7; k7 = SENT;
            }
        }
        if (lane < KNN) {
            int j = (int)(unsigned int)(mywin & 0xFFFFFFFFull);
            idx[(b * MNODE + i) * KNN + lane] = j;
            atomicAdd(&cnt[b * MNODE + j], 1);
        }
    }
}

// fused: dinv[j] + PS[j] (pre-folded dinv*S) + per-block cnt sums for the scan
__global__ void __launch_bounds__(256) dinv_scanblk_kernel(
    const int* __restrict__ cnt, const float* __restrict__ S,
    float* __restrict__ dinv, float* __restrict__ PS, int* __restrict__ bsum) {
    __shared__ int wsum[4];
    int tid = threadIdx.x;
    int gid = blockIdx.x * 256 + tid;
    int c = cnt[gid];
    float deg = (float)(KNN + c);
    float dv = 1.0f / sqrtf(deg + 1e-8f);
    dinv[gid] = dv;
    PS[gid * 2 + 0] = dv * S[gid * 2 + 0];
    PS[gid * 2 + 1] = dv * S[gid * 2 + 1];
    int s = c;
    #pragma unroll
    for (int off = 32; off > 0; off >>= 1) s += __shfl_down(s, off, 64);
    if ((tid & 63) == 0) wsum[tid >> 6] = s;
    __syncthreads();
    if (tid == 0) bsum[blockIdx.x] = wsum[0] + wsum[1] + wsum[2] + wsum[3];
}

// scan_apply with self-computed base: base = sum of bsum[t] for t < blockIdx.x
// (masked block-reduce over the 144 block sums), then in-block wave scan.
__global__ void __launch_bounds__(256) scan_apply_kernel(const int* __restrict__ cnt,
                                                         const int* __restrict__ bsum,
                                                         int* __restrict__ offs) {
    __shared__ int wsum[4];
    __shared__ int sbase[4];
    int tid = threadIdx.x;
    int lane = tid & 63, wv = tid >> 6;
    int bb = 0;
    if (tid < NBLK && tid < (int)blockIdx.x) bb = bsum[tid];
    #pragma unroll
    for (int off = 32; off > 0; off >>= 1) bb += __shfl_down(bb, off, 64);
    if (lane == 0) sbase[wv] = bb;
    int gid = blockIdx.x * 256 + tid;
    int v = cnt[gid];
    int x = v;
    #pragma unroll
    for (int off = 1; off < 64; off <<= 1) {
        int y = __shfl_up(x, off, 64);
        if (lane >= off) x += y;
    }
    if (lane == 63) wsum[wv] = x;
    __syncthreads();
    int base = sbase[0] + sbase[1] + sbase[2] + sbase[3];
    for (int w = 0; w < wv; ++w) base += wsum[w];
    offs[gid] = base + x - v;
}

// scatter each directed edge i->j into j's reverse list (int atomics for slots)
__global__ void fill_kernel(const int* __restrict__ idx, const int* __restrict__ offs,
                            int* __restrict__ fptr, int* __restrict__ rev) {
    int gid = blockIdx.x * blockDim.x + threadIdx.x;
    if (gid >= BM * KNN) return;
    int b = gid / (MNODE * KNN);
    int rem = gid - b * (MNODE * KNN);
    int i = rem / KNN;
    int gj = b * MNODE + idx[gid];
    int pos = atomicAdd(&fptr[gj], 1);
    rev[offs[gj] + pos] = b * MNODE + i;
}

// zA[i][c] = 0.5*dinv[i] * sum over neighbors j (both directions) with j%9==c of PS[j]
// 4 threads per row (c-quarters {0-2},{3-4},{5-6},{7-8}); static 6-float acc.
__global__ void __launch_bounds__(256) gather1_kernel(
    const int* __restrict__ idx, const int* __restrict__ offs, const int* __restrict__ cnt,
    const int* __restrict__ rev, const float* __restrict__ dinv, const float* __restrict__ PS,
    float* __restrict__ zA) {
    int gid = blockIdx.x * blockDim.x + threadIdx.x;
    if (gid >= BM * 4) return;
    int gi = gid >> 2;
    int q = gid & 3;
    int c0 = (q == 0) ? 0 : (1 + 2 * q);          // 0,3,5,7
    int nc = (q == 0) ? 3 : 2;
    int b = gi / MNODE;
    float a0 = 0.0f, a1 = 0.0f, a2 = 0.0f, a3 = 0.0f, a4 = 0.0f, a5 = 0.0f;
    #pragma unroll
    for (int k = 0; k < KNN; ++k) {
        int gj = b * MNODE + idx[gi * KNN + k];
        int rel = gj % CFREQ - c0;
        float2 p = ((const float2*)PS)[gj];
        bool t0 = (rel == 0), t1 = (rel == 1), t2 = (rel == 2) && (nc == 3);
        a0 += t0 ? p.x : 0.0f;  a1 += t0 ? p.y : 0.0f;
        a2 += t1 ? p.x : 0.0f;  a3 += t1 ? p.y : 0.0f;
        a4 += t2 ? p.x : 0.0f;  a5 += t2 ? p.y : 0.0f;
    }
    int o = offs[gi], e = o + cnt[gi];
    for (int p_ = o; p_ < e; ++p_) {
        int gk = rev[p_];
        int rel = gk % CFREQ - c0;
        float2 p = ((const float2*)PS)[gk];
        bool t0 = (rel == 0), t1 = (rel == 1), t2 = (rel == 2) && (nc == 3);
        a0 += t0 ? p.x : 0.0f;  a1 += t0 ? p.y : 0.0f;
        a2 += t1 ? p.x : 0.0f;  a3 += t1 ? p.y : 0.0f;
        a4 += t2 ? p.x : 0.0f;  a5 += t2 ? p.y : 0.0f;
    }
    float s = dinv[gi] * 0.5f;
    zA[(gi * CFREQ + c0 + 0) * 2 + 0] = s * a0;
    zA[(gi * CFREQ + c0 + 0) * 2 + 1] = s * a1;
    zA[(gi * CFREQ + c0 + 1) * 2 + 0] = s * a2;
    zA[(gi * CFREQ + c0 + 1) * 2 + 1] = s * a3;
    if (nc == 3) {
        zA[(gi * CFREQ + c0 + 2) * 2 + 0] = s * a4;
        zA[(gi * CFREQ + c0 + 2) * 2 + 1] = s * a5;
    }
}

// zB[i][c] = sum over neighbors j (both directions) of w_ij * zA[j][c]
// 4 threads per row (c-quarters) for occupancy.
__global__ void __launch_bounds__(256) gather2_kernel(
    const int* __restrict__ idx, const int* __restrict__ offs, const int* __restrict__ cnt,
    const int* __restrict__ rev, const float* __restrict__ dinv, const float* __restrict__ zA,
    float* __restrict__ zB) {
    int gid = blockIdx.x * blockDim.x + threadIdx.x;
    if (gid >= BM * 4) return;
    int gi = gid >> 2;
    int q = gid & 3;
    int c0 = (q == 0) ? 0 : (1 + 2 * q);          // 0,3,5,7
    int nc = (q == 0) ? 3 : 2;
    int b = gi / MNODE;
    float acc[6];
    #pragma unroll
    for (int k = 0; k < 6; ++k) acc[k] = 0.0f;
    float di = dinv[gi] * 0.5f;
    #pragma unroll
    for (int k = 0; k < KNN; ++k) {
        int gj = b * MNODE + idx[gi * KNN + k];
        float w = di * dinv[gj];
        const float2* za = (const float2*)(zA + gj * 2 * CFREQ) + c0;
        #pragma unroll
        for (int c = 0; c < 3; ++c) {
            if (c < nc) {
                float2 v = za[c];
                acc[2 * c + 0] += w * v.x;
                acc[2 * c + 1] += w * v.y;
            }
        }
    }
    int o = offs[gi], e = o + cnt[gi];
    for (int p = o; p < e; ++p) {
        int gk = rev[p];
        float w = di * dinv[gk];
        const float2* za = (const float2*)(zA + gk * 2 * CFREQ) + c0;
        #pragma unroll
        for (int c = 0; c < 3; ++c) {
            if (c < nc) {
                float2 v = za[c];
                acc[2 * c + 0] += w * v.x;
                acc[2 * c + 1] += w * v.y;
            }
        }
    }
    #pragma unroll
    for (int c = 0; c < 3; ++c) {
        if (c < nc) {
            zB[(gi * CFREQ + c0 + c) * 2 + 0] = acc[2 * c + 0];
            zB[(gi * CFREQ + c0 + c) * 2 + 1] = acc[2 * c + 1];
        }
    }
}

// FE[c,e] = freq_emb[c,:] @ (Wr + i Wi)^T  (9 x 128 complex)
__global__ void fe_kernel(const float* __restrict__ femb, const float* __restrict__ Wr,
                          const float* __restrict__ Wi, float* __restrict__ FE) {
    int gid = blockIdx.x * blockDim.x + threadIdx.x;
    if (gid >= CFREQ * EMBED) return;
    int c = gid / EMBED;
    int e = gid - c * EMBED;
    float ar = 0.0f, ai = 0.0f;
    for (int k = 0; k < EMBED; ++k) {
        float f = femb[c * EMBED + k];
        ar += f * Wr[e * EMBED + k];
        ai += f * Wi[e * EMBED + k];
    }
    FE[gid * 2 + 0] = ar;
    FE[gid * 2 + 1] = ai;
}

// per row r: z_acc (9 complex) -> u = z_acc . FE -> csilu -> eo projection (complex scalar)
__global__ void __launch_bounds__(256) rowproj_kernel(
    const float* __restrict__ S, const float* __restrict__ zA, const float* __restrict__ zB,
    const float* __restrict__ FE, const float* __restrict__ eoWr, const float* __restrict__ eoWi,
    const float* __restrict__ theta, const float* __restrict__ approx,
    float* __restrict__ Sout) {
    int wave = threadIdx.x >> 6;
    int lane = threadIdx.x & 63;
    int r = blockIdx.x * 4 + wave;
    if (r >= BM) return;
    float a0 = theta[0] * approx[0] + theta[1] * approx[3];
    float a1 = theta[0] * approx[1] + theta[1] * approx[4];
    float a2 = theta[0] * approx[2] + theta[1] * approx[5];
    float ca = a0 - a2, cb = -a1, cc = 2.0f * a2;
    int cr = r % CFREQ;
    float sr = S[r * 2 + 0], si = S[r * 2 + 1];
    int e1 = lane + 64;
    float ur0 = 0.0f, ui0 = 0.0f, ur1 = 0.0f, ui1 = 0.0f;
    #pragma unroll
    for (int c = 0; c < CFREQ; ++c) {
        float zr = cb * zA[(r * CFREQ + c) * 2 + 0] + cc * zB[(r * CFREQ + c) * 2 + 0];
        float zi = cb * zA[(r * CFREQ + c) * 2 + 1] + cc * zB[(r * CFREQ + c) * 2 + 1];
        if (c == cr) { zr += ca * sr; zi += ca * si; }
        float fr0 = FE[(c * EMBED + lane) * 2 + 0], fi0 = FE[(c * EMBED + lane) * 2 + 1];
        float fr1 = FE[(c * EMBED + e1) * 2 + 0],  fi1 = FE[(c * EMBED + e1) * 2 + 1];
        ur0 += zr * fr0 - zi * fi0;  ui0 += zr * fi0 + zi * fr0;
        ur1 += zr * fr1 - zi * fi1;  ui1 += zr * fi1 + zi * fr1;
    }
    float hr0 = silu_f(ur0), hi0 = silu_f(ui0);
    float hr1 = silu_f(ur1), hi1 = silu_f(ui1);
    float wr0 = eoWr[lane], wi0 = eoWi[lane], wr1 = eoWr[e1], wi1 = eoWi[e1];
    float p = hr0 * wr0 - hi0 * wi0 + hr1 * wr1 - hi1 * wi1;
    float q = hr0 * wi0 + hi0 * wr0 + hr1 * wi1 + hi1 * wr1;
    #pragma unroll
    for (int off = 32; off > 0; off >>= 1) {
        p += __shfl_down(p, off, 64);
        q += __shfl_down(q, off, 64);
    }
    if (lane == 0) {
        Sout[r * 2 + 0] = p;
        Sout[r * 2 + 1] = q;
    }
}

// per (b,n): irfft96 -> inorm+silu -> W1 -> inorm+silu -> W2 -> + trend_emb -> W3 -> out
// HROWS=4 rows per 256-thread block: weight staging amortized 4x, matvec
// phases use wave g's 64 lanes = row g's 64 outputs (100% utilization),
// inorm2 is pure in-wave shuffles.
__global__ void __launch_bounds__(256) head_kernel(
    const float* __restrict__ Sout, const float* __restrict__ trend,
    const float* __restrict__ n1w, const float* __restrict__ n1b,
    const float* __restrict__ n2w, const float* __restrict__ n2b,
    const float* __restrict__ W1w, const float* __restrict__ W1b,
    const float* __restrict__ W2w, const float* __restrict__ W2b,
    const float* __restrict__ Wtw, const float* __restrict__ Wtb,
    const float* __restrict__ W3w, const float* __restrict__ W3b,
    float* __restrict__ out) {
    __shared__ float tabc[96], tabs[96];
    __shared__ float srow[HROWS][18];
    __shared__ float tbuf[HROWS][96];
    __shared__ float hraw[HROWS][96];
    __shared__ float sH[HROWS][96];
    __shared__ float h2[HROWS][64];
    __shared__ float s3[HROWS][64];
    __shared__ float red[HROWS][2];
    __shared__ float wbuf[6240];
    int tid = threadIdx.x;
    int wave = tid >> 6, lane = tid & 63;
    int bn0 = blockIdx.x * HROWS;
    if (tid < 96) {
        double a = 6.283185307179586476925286766559 * (double)tid / 96.0;
        tabc[tid] = (float)cos(a);
        tabs[tid] = (float)sin(a);
    }
    for (int i = tid; i < HROWS * 96; i += 256) {
        int g = i / 96, t = i - g * 96;
        int bn = bn0 + g;
        tbuf[g][t] = trend[(bn >> 8) * TN + t * NNODE + (bn & 255)];
    }
    if (tid < HROWS * 18) {
        int g = tid / 18, k = tid - g * 18;
        srow[g][k] = Sout[(bn0 + g) * 18 + k];
    }
    __syncthreads();
    // irfft96 for all 4 rows
    for (int i = tid; i < HROWS * 96; i += 256) {
        int g = i / 96, t = i - g * 96;
        float acc = srow[g][0];   // Im(bin0) ignored by irfft
        #pragma unroll
        for (int c = 1; c < CFREQ; ++c) {
            int k = (c * t) % 96;
            acc += 2.0f * (srow[g][2 * c] * tabc[k] - srow[g][2 * c + 1] * tabs[k]);
        }
        hraw[g][t] = acc * 0.10206207261596575f;  // 1/sqrt(96)
    }
    __syncthreads();
    // mean of row `wave`
    {
        float v = hraw[wave][lane] + ((lane < 32) ? hraw[wave][64 + lane] : 0.0f);
        #pragma unroll
        for (int off = 32; off > 0; off >>= 1) v += __shfl_down(v, off, 64);
        if (lane == 0) red[wave][0] = v * (1.0f / 96.0f);
    }
    __syncthreads();
    // var of row `wave`
    {
        float mu = red[wave][0];
        float d0 = hraw[wave][lane] - mu;
        float v = d0 * d0;
        if (lane < 32) { float d1 = hraw[wave][64 + lane] - mu; v += d1 * d1; }
        #pragma unroll
        for (int off = 32; off > 0; off >>= 1) v += __shfl_down(v, off, 64);
        if (lane == 0) red[wave][1] = v * (1.0f / 96.0f);
    }
    __syncthreads();
    // inorm1 + silu -> sH; stage W1 (97-pad)
    for (int i = tid; i < HROWS * 96; i += 256) {
        int g = i / 96, t = i - g * 96;
        int n = (bn0 + g) & 255;
        float xn = (hraw[g][t] - red[g][0]) / sqrtf(red[g][1] + 1e-5f) * n1w[n] + n1b[n];
        sH[g][t] = silu_f(xn);
    }
    for (int i = tid; i < HIDDEN * 96; i += 256) {
        int rr = i / 96;
        wbuf[rr * 97 + (i - rr * 96)] = W1w[i];
    }
    __syncthreads();
    // W1 matvec: wave g, lane r
    float v1;
    {
        float acc = W1b[lane];
        #pragma unroll 8
        for (int t = 0; t < 96; ++t) acc += sH[wave][t] * wbuf[lane * 97 + t];
        v1 = acc;
    }
    // inorm2 + silu (pure in-wave) -> h2
    {
        float s = v1;
        #pragma unroll
        for (int off = 32; off > 0; off >>= 1) s += __shfl_down(s, off, 64);
        s = __shfl(s, 0, 64);
        float mu2 = s * (1.0f / 64.0f);
        float d = v1 - mu2;
        float vs = d * d;
        #pragma unroll
        for (int off = 32; off > 0; off >>= 1) vs += __shfl_down(vs, off, 64);
        vs = __shfl(vs, 0, 64);
        float var2 = vs * (1.0f / 64.0f);
        int n = (bn0 + wave) & 255;
        float xn = (v1 - mu2) / sqrtf(var2 + 1e-5f) * n2w[n] + n2b[n];
        h2[wave][lane] = silu_f(xn);
    }
    __syncthreads();   // wbuf(W1) reads + h2 writes done
    for (int i = tid; i < HIDDEN * HIDDEN; i += 256) {
        wbuf[(i >> 6) * 65 + (i & 63)] = W2w[i];
    }
    __syncthreads();
    float v3;
    {
        float acc = W2b[lane];
        #pragma unroll 8
        for (int h = 0; h < 64; ++h) acc += h2[wave][h] * wbuf[lane * 65 + h];
        v3 = acc;
    }
    __syncthreads();   // wbuf(W2) reads done
    for (int i = tid; i < HIDDEN * 96; i += 256) {
        int rr = i / 96;
        wbuf[rr * 97 + (i - rr * 96)] = Wtw[i];
    }
    __syncthreads();
    {
        float acc = Wtb[lane];
        #pragma unroll 8
        for (int t = 0; t < 96; ++t) acc += tbuf[wave][t] * wbuf[lane * 97 + t];
        s3[wave][lane] = v3 + acc;
    }
    __syncthreads();   // wbuf(Wt) reads + s3 writes done
    for (int i = tid; i < 96 * HIDDEN; i += 256) {
        wbuf[(i >> 6) * 65 + (i & 63)] = W3w[i];
    }
    __syncthreads();
    for (int i = tid; i < HROWS * 96; i += 256) {
        int g = i / 96, t = i - g * 96;
        float acc = W3b[t];
        #pragma unroll 8
        for (int h = 0; h < 64; ++h) acc += s3[g][h] * wbuf[t * 65 + h];
        out[(bn0 + g) * 96 + t] = acc;
    }
}

extern "C" void kernel_launch(void* const* d_in, const int* in_sizes, int n_in,
                              void* d_out, int out_size, void* d_ws, size_t ws_size,
                              hipStream_t stream) {
    const float* x     = (const float*)d_in[0];
    const float* approx= (const float*)d_in[1];
    const float* theta = (const float*)d_in[2];
    const float* frWr  = (const float*)d_in[3];
    const float* frWi  = (const float*)d_in[4];
    const float* eoWr  = (const float*)d_in[5];
    const float* eoWi  = (const float*)d_in[6];
    const float* femb  = (const float*)d_in[7];
    const float* n1w   = (const float*)d_in[8];
    const float* n1b   = (const float*)d_in[9];
    const float* n2w   = (const float*)d_in[10];
    const float* n2b   = (const float*)d_in[11];
    const float* W1w   = (const float*)d_in[12];
    const float* W1b   = (const float*)d_in[13];
    const float* W2w   = (const float*)d_in[14];
    const float* W2b   = (const float*)d_in[15];
    const float* Wtw   = (const float*)d_in[16];
    const float* Wtb   = (const float*)d_in[17];
    const float* W3w   = (const float*)d_in[18];
    const float* W3b   = (const float*)d_in[19];
    float* out = (float*)d_out;

    char* ws = (char*)d_ws;
    size_t off = 0;
    auto alloc = [&](size_t bytes) -> void* {
        void* p = ws + off;
        off = (off + bytes + 255) & ~(size_t)255;
        return p;
    };
    float* trend = (float*)alloc((size_t)BATCH * TN * 4);
    float* S     = (float*)alloc((size_t)BM * 2 * 4);
    int*   idx   = (int*)  alloc((size_t)BM * KNN * 4);
    float* dinv  = (float*)alloc((size_t)BM * 4);
    float* PS    = (float*)alloc((size_t)BM * 2 * 4);
    float* FE    = (float*)alloc((size_t)CFREQ * EMBED * 2 * 4);
    float* Sout  = (float*)alloc((size_t)BM * 2 * 4);
    int*   offs  = (int*)  alloc((size_t)BM * 4);
    int*   rev   = (int*)  alloc((size_t)BM * KNN * 4);
    float* zA    = (float*)alloc((size_t)BM * CFREQ * 2 * 4);
    float* zB    = (float*)alloc((size_t)BM * CFREQ * 2 * 4);
    int*   bsum  = (int*)  alloc((size_t)NBLK * 4);
    char*  zbase = ws + off;
    int*   cnt   = (int*)  alloc((size_t)BM * 4);
    int*   fptr  = (int*)  alloc((size_t)BM * 4);
    size_t zbytes = (size_t)(ws + off - zbase);

    hipMemsetAsync(zbase, 0, zbytes, stream);   // cnt + fptr only (288 KB)

    trend_kernel<<<(BATCH * TN + 255) / 256, 256, 0, stream>>>(x, trend);
    fft_kernel<<<(BM + 255) / 256, 256, 0, stream>>>(x, trend, S);
    knn_kernel<<<dim3(MNODE / 4, BATCH), 256, 0, stream>>>(S, idx, cnt);
    dinv_scanblk_kernel<<<NBLK, 256, 0, stream>>>(cnt, S, dinv, PS, bsum);
    scan_apply_kernel<<<NBLK, 256, 0, stream>>>(cnt, bsum, offs);
    fill_kernel<<<(BM * KNN + 255) / 256, 256, 0, stream>>>(idx, offs, fptr, rev);
    gather1_kernel<<<(BM * 4 + 255) / 256, 256, 0, stream>>>(idx, offs, cnt, rev, dinv, PS, zA);
    gather2_kernel<<<(BM * 4 + 255) / 256, 256, 0, stream>>>(idx, offs, cnt, rev, dinv, zA, zB);
    fe_kernel<<<(CFREQ * EMBED + 255) / 256, 256, 0, stream>>>(femb, frWr, frWi, FE);
    rowproj_kernel<<<BM / 4, 256, 0, stream>>>(S, zA, zB, FE, eoWr, eoWi, theta, approx, Sout);
    head_kernel<<<BATCH * NNODE / HROWS, 256, 0, stream>>>(Sout, trend, n1w, n1b, n2w, n2b,
                                                           W1w, W1b, W2w, W2b, Wtw, Wtb, W3w, W3b, out);
}